// Round 11
// baseline (1062.046 us; speedup 1.0000x reference)
//
#include <hip/hip_runtime.h>
#include <stdint.h>

#define NN 50000
#define NPAD 50048          // 391*128
#define NE 800000
#define DD 256
#define NL 4

typedef __attribute__((ext_vector_type(8))) _Float16 half8;
typedef __attribute__((ext_vector_type(4))) float f32x4;
typedef __attribute__((ext_vector_type(8))) float f32x8;
typedef __attribute__((ext_vector_type(8))) unsigned short ushort8_t;

__device__ inline unsigned short f2h(float x) {
    union { _Float16 h; unsigned short u; } v;
    v.h = (_Float16)x;
    return v.u;
}
__device__ inline float h2f(unsigned short u) {
    union { unsigned short u; _Float16 h; } v;
    v.u = u;
    return (float)v.h;
}

// ---- zero all sums buffers (12x512) + deg ----
__global__ void zeroall_k(float* __restrict__ sums, int* __restrict__ deg) {
    int i = blockIdx.x * 256 + threadIdx.x;
    if (i < NL * 3 * 512) sums[i] = 0.f;
    if (i < NN) deg[i] = 0;
}

// ---- convert W [L][K][N] fp32 -> Wt [L][N][K] fp16 ----
__global__ void wconv_k(const float* __restrict__ W, unsigned short* __restrict__ Wt) {
    int idx = blockIdx.x * 256 + threadIdx.x;
    int l   = idx >> 16;
    int rem = idx & 0xFFFF;
    int k   = rem >> 8;
    int n   = rem & 255;
    float x = W[(l << 16) + (k << 8) + n];
    Wt[(l << 16) + (n << 8) + k] = f2h(x);
}

// ---- convert h_in fp32 -> h16 fp16 (layer 0 only) ----
__global__ void h16conv_k(const float4* __restrict__ H, unsigned short* __restrict__ h16) {
    int i = blockIdx.x * 256 + threadIdx.x;    // over NN*64
    float4 v = H[i];
    ushort4 u;
    u.x = f2h(v.x); u.y = f2h(v.y); u.z = f2h(v.z); u.w = f2h(v.w);
    *(ushort4*)(h16 + (size_t)i * 4) = u;
}

// ======================= CSR build (once) =======================
__global__ void hist_k(const int* __restrict__ ei, int* __restrict__ deg) {
    int e = blockIdx.x * 256 + threadIdx.x;
    if (e < NE) atomicAdd(&deg[ei[NE + e]], 1);
}

__global__ void bsum_k(const int* __restrict__ deg, int* __restrict__ bsum) {
    __shared__ int sm[256];
    int i = blockIdx.x * 256 + threadIdx.x;
    sm[threadIdx.x] = (i < NN) ? deg[i] : 0;
    __syncthreads();
    for (int off = 128; off > 0; off >>= 1) {
        if (threadIdx.x < off) sm[threadIdx.x] += sm[threadIdx.x + off];
        __syncthreads();
    }
    if (threadIdx.x == 0) bsum[blockIdx.x] = sm[0];
}

__global__ void bscan_k(const int* __restrict__ bsum, int* __restrict__ boff) {
    __shared__ int sm[256];
    int t = threadIdx.x;
    int v = (t < 196) ? bsum[t] : 0;
    sm[t] = v; __syncthreads();
    for (int off = 1; off < 256; off <<= 1) {
        int u = (t >= off) ? sm[t - off] : 0;
        __syncthreads();
        sm[t] += u;
        __syncthreads();
    }
    boff[t] = sm[t] - v;
}

__global__ void rowptr_k(const int* __restrict__ deg, const int* __restrict__ boff,
                         int* __restrict__ rowptr, int* __restrict__ cursor) {
    __shared__ int sm[256];
    int b = blockIdx.x, t = threadIdx.x;
    int i = b * 256 + t;
    int v = (i < NN) ? deg[i] : 0;
    sm[t] = v; __syncthreads();
    for (int off = 1; off < 256; off <<= 1) {
        int u = (t >= off) ? sm[t - off] : 0;
        __syncthreads();
        sm[t] += u;
        __syncthreads();
    }
    int excl = boff[b] + sm[t] - v;
    if (i < NN) { rowptr[i] = excl; cursor[i] = excl; }
    if (i == NN - 1) rowptr[NN] = excl + v;
}

__global__ void fill_k(const int* __restrict__ ei, int* __restrict__ cursor,
                       int* __restrict__ csr) {
    int e = blockIdx.x * 256 + threadIdx.x;
    if (e < NE) {
        int d = ei[NE + e];
        int p = atomicAdd(&cursor[d], 1);
        csr[p] = ei[e];
    }
}

// ======================= per-layer gather (fp16, 2 rows/wave-step) =======================
__global__ void gather_k(const int* __restrict__ rowptr, const int* __restrict__ csr,
                         const unsigned short* __restrict__ h16,
                         unsigned short* __restrict__ rb) {
    int w    = threadIdx.x >> 6;
    int lane = threadIdx.x & 63;
    int node = blockIdx.x * 4 + w;
    if (node >= NPAD) return;
    int half = lane >> 5;
    int l32  = lane & 31;
    int c    = l32 * 8;
    unsigned short* dst = rb + (size_t)node * DD + c;
    if (node >= NN) {
        if (half == 0) {
            ushort8_t z = {0,0,0,0,0,0,0,0};
            *(ushort8_t*)dst = z;
        }
        return;
    }
    int beg = rowptr[node], end = rowptr[node + 1];
    f32x8 acc = {0.f,0.f,0.f,0.f,0.f,0.f,0.f,0.f};
    if (half == 0) {
        ushort8_t hv = *(const ushort8_t*)(h16 + (size_t)node * DD + c);
        #pragma unroll
        for (int k = 0; k < 8; ++k) acc[k] = h2f(hv[k]);
    }
    int j = beg;
    for (; j + 8 <= end; j += 8) {
        int j0 = csr[j + half], j1 = csr[j + 2 + half];
        int j2 = csr[j + 4 + half], j3 = csr[j + 6 + half];
        ushort8_t v0 = *(const ushort8_t*)(h16 + (size_t)j0 * DD + c);
        ushort8_t v1 = *(const ushort8_t*)(h16 + (size_t)j1 * DD + c);
        ushort8_t v2 = *(const ushort8_t*)(h16 + (size_t)j2 * DD + c);
        ushort8_t v3 = *(const ushort8_t*)(h16 + (size_t)j3 * DD + c);
        #pragma unroll
        for (int k = 0; k < 8; ++k)
            acc[k] += (h2f(v0[k]) + h2f(v1[k])) + (h2f(v2[k]) + h2f(v3[k]));
    }
    for (; j + 2 <= end; j += 2) {
        int jj = csr[j + half];
        ushort8_t v0 = *(const ushort8_t*)(h16 + (size_t)jj * DD + c);
        #pragma unroll
        for (int k = 0; k < 8; ++k) acc[k] += h2f(v0[k]);
    }
    if (j < end && half == 0) {
        int jj = csr[j];
        ushort8_t v0 = *(const ushort8_t*)(h16 + (size_t)jj * DD + c);
        #pragma unroll
        for (int k = 0; k < 8; ++k) acc[k] += h2f(v0[k]);
    }
    #pragma unroll
    for (int k = 0; k < 8; ++k) acc[k] += __shfl_xor(acc[k], 32);
    if (half == 0) {
        ushort8_t u;
        #pragma unroll
        for (int k = 0; k < 8; ++k) u[k] = f2h(acc[k]);
        *(ushort8_t*)dst = u;
    }
}

// ====== GEMM 128x128 tile, 4 waves (2x2), BK=32, fp16 MFMA, grid (391,2) ======
#define GEMM_EPILOGUE(CPTR, SUMS)                                                \
    _Pragma("unroll")                                                            \
    for (int nf = 0; nf < 4; ++nf) {                                             \
        int gcol = nbase + wc * 64 + nf * 16 + l15;                              \
        float bs = bias[gcol];                                                   \
        float s = 0.f, s2 = 0.f;                                                 \
        _Pragma("unroll")                                                        \
        for (int mf = 0; mf < 4; ++mf) {                                         \
            int r0 = mbase + wr * 64 + mf * 16 + l4 * 4;                         \
            _Pragma("unroll")                                                    \
            for (int j = 0; j < 4; ++j) {                                        \
                int row = r0 + j;                                                \
                if (row < NN) {                                                  \
                    float cv = acc[mf][nf][j] + bs;                              \
                    CPTR[(size_t)row * DD + gcol] = f2h(cv);                     \
                    s += cv; s2 += cv * cv;                                      \
                }                                                                \
            }                                                                    \
        }                                                                        \
        s  += __shfl_xor(s, 16);  s  += __shfl_xor(s, 32);                       \
        s2 += __shfl_xor(s2, 16); s2 += __shfl_xor(s2, 32);                      \
        if (l4 == 0) {                                                           \
            atomicAdd(&SUMS[gcol], s);                                           \
            atomicAdd(&SUMS[DD + gcol], s2);                                     \
        }                                                                        \
    }

#define GEMM_MFMA_STEP()                                                         \
    {                                                                            \
        half8 af[4], bf[4];                                                      \
        _Pragma("unroll")                                                        \
        for (int mf = 0; mf < 4; ++mf)                                           \
            af[mf] = *(const half8*)&As[wr * 64 + mf * 16 + l15][l4 * 8];        \
        _Pragma("unroll")                                                        \
        for (int nf = 0; nf < 4; ++nf)                                           \
            bf[nf] = *(const half8*)&Bs[wc * 64 + nf * 16 + l15][l4 * 8];        \
        _Pragma("unroll")                                                        \
        for (int mf = 0; mf < 4; ++mf)                                           \
            _Pragma("unroll")                                                    \
            for (int nf = 0; nf < 4; ++nf)                                       \
                acc[mf][nf] = __builtin_amdgcn_mfma_f32_16x16x32_f16(            \
                    af[mf], bf[nf], acc[mf][nf], 0, 0, 0);                       \
    }

// GEMM1: A fp16 (rb, zero-padded rows), t1 = A @ Wt^T + b ; stats -> sums1
__global__ __launch_bounds__(256)
void gemm_f16_k(const unsigned short* __restrict__ A,
                const unsigned short* __restrict__ Wt,
                const float* __restrict__ bias,
                unsigned short* __restrict__ C, float* __restrict__ sums1) {
    __shared__ unsigned short As[128][40];
    __shared__ unsigned short Bs[128][40];
    const int tid   = threadIdx.x;
    const int mbase = blockIdx.x * 128;
    const int nbase = blockIdx.y * 128;
    const int wave  = tid >> 6, lane = tid & 63;
    const int wr = wave >> 1, wc = wave & 1;
    const int l15 = lane & 15, l4 = lane >> 4;

    f32x4 acc[4][4] = {};

    for (int ks = 0; ks < 8; ++ks) {
        const int k0 = ks * 32;
        // A: 128x32 fp16 = 8KB = 256 thr x 2 x 16B
        #pragma unroll
        for (int sI = 0; sI < 2; ++sI) {
            int q = sI * 256 + tid;
            int row = q >> 2, seg = (q & 3) * 8;
            uint4 wv = *(const uint4*)(A + (size_t)(mbase + row) * DD + k0 + seg);
            *(uint4*)&As[row][seg] = wv;
        }
        // B: 128x32 fp16 = 8KB
        #pragma unroll
        for (int sI = 0; sI < 2; ++sI) {
            int q = sI * 256 + tid;
            int col = q >> 2, seg = (q & 3) * 8;
            uint4 wv = *(const uint4*)(Wt + (size_t)(nbase + col) * DD + k0 + seg);
            *(uint4*)&Bs[col][seg] = wv;
        }
        __syncthreads();
        GEMM_MFMA_STEP()
        __syncthreads();
    }
    GEMM_EPILOGUE(C, sums1)
}

// GEMM2: A fp16 (t1); BN1 (inline fin from sums1) + ReLU at staging; stats -> sums2
__global__ __launch_bounds__(256)
void gemm_bn_k(const unsigned short* __restrict__ A,
               const unsigned short* __restrict__ Wt,
               const float* __restrict__ bias,
               const float* __restrict__ sums1,
               const float* __restrict__ g1, const float* __restrict__ bb1,
               unsigned short* __restrict__ C, float* __restrict__ sums2) {
    __shared__ unsigned short As[128][40];
    __shared__ unsigned short Bs[128][40];
    __shared__ float sc_l[DD], sh_l[DD];
    const int tid   = threadIdx.x;
    const int mbase = blockIdx.x * 128;
    const int nbase = blockIdx.y * 128;
    const int wave  = tid >> 6, lane = tid & 63;
    const int wr = wave >> 1, wc = wave & 1;
    const int l15 = lane & 15, l4 = lane >> 4;

    // inline fin1 (256 threads cover DD=256)
    {
        float s = sums1[tid], s2 = sums1[DD + tid];
        float mu  = s * (1.f / NN);
        float var = s2 * (1.f / NN) - mu * mu;
        float a = rsqrtf(var + 1e-5f) * g1[tid];
        sc_l[tid] = a;
        sh_l[tid] = bb1[tid] - mu * a;
    }

    f32x4 acc[4][4] = {};

    for (int ks = 0; ks < 8; ++ks) {
        const int k0 = ks * 32;
        if (ks == 0) __syncthreads();   // sc_l/sh_l ready
        #pragma unroll
        for (int sI = 0; sI < 2; ++sI) {
            int q = sI * 256 + tid;
            int row = q >> 2, seg = (q & 3) * 8;
            int grow = mbase + row;
            uint4 wv = {0u, 0u, 0u, 0u};
            if (grow < NN) wv = *(const uint4*)(A + (size_t)grow * DD + k0 + seg);
            unsigned short* ph = (unsigned short*)&wv;
            int cb = k0 + seg;
            ushort4 u0, u1;
            u0.x = f2h(fmaxf(h2f(ph[0]) * sc_l[cb+0] + sh_l[cb+0], 0.f));
            u0.y = f2h(fmaxf(h2f(ph[1]) * sc_l[cb+1] + sh_l[cb+1], 0.f));
            u0.z = f2h(fmaxf(h2f(ph[2]) * sc_l[cb+2] + sh_l[cb+2], 0.f));
            u0.w = f2h(fmaxf(h2f(ph[3]) * sc_l[cb+3] + sh_l[cb+3], 0.f));
            u1.x = f2h(fmaxf(h2f(ph[4]) * sc_l[cb+4] + sh_l[cb+4], 0.f));
            u1.y = f2h(fmaxf(h2f(ph[5]) * sc_l[cb+5] + sh_l[cb+5], 0.f));
            u1.z = f2h(fmaxf(h2f(ph[6]) * sc_l[cb+6] + sh_l[cb+6], 0.f));
            u1.w = f2h(fmaxf(h2f(ph[7]) * sc_l[cb+7] + sh_l[cb+7], 0.f));
            *(ushort4*)&As[row][seg] = u0;
            *(ushort4*)&As[row][seg + 4] = u1;
        }
        #pragma unroll
        for (int sI = 0; sI < 2; ++sI) {
            int q = sI * 256 + tid;
            int col = q >> 2, seg = (q & 3) * 8;
            uint4 wv = *(const uint4*)(Wt + (size_t)(nbase + col) * DD + k0 + seg);
            *(uint4*)&Bs[col][seg] = wv;
        }
        __syncthreads();
        GEMM_MFMA_STEP()
        __syncthreads();
    }
    GEMM_EPILOGUE(C, sums2)
}

// ---- BN3 stats over m = relu(BN2(t2)); BN2 inline fin from sums2; stats -> sums3 ----
__global__ void bn_stats_k(const unsigned short* __restrict__ X,
                           const float* __restrict__ sums2,
                           const float* __restrict__ g2, const float* __restrict__ bb2,
                           float* __restrict__ sums3) {
    __shared__ float4 sA[256];
    __shared__ float4 sB[256];
    __shared__ float sc_l[DD], sh_l[DD];
    int t  = threadIdx.x;
    if (t < DD) {
        float s = sums2[t], s2v = sums2[DD + t];
        float mu  = s * (1.f / NN);
        float var = s2v * (1.f / NN) - mu * mu;
        float a = rsqrtf(var + 1e-5f) * g2[t];
        sc_l[t] = a;
        sh_l[t] = bb2[t] - mu * a;
    }
    __syncthreads();
    int rs = t >> 6;
    int c4 = t & 63;
    int c  = c4 * 4;
    float4 a = *(const float4*)(sc_l + c), b = *(const float4*)(sh_l + c);
    float4 s = {0.f,0.f,0.f,0.f}, s2 = {0.f,0.f,0.f,0.f};
    for (int r4 = blockIdx.x; r4 < NN / 4; r4 += gridDim.x) {
        int row = r4 * 4 + rs;
        ushort4 xu = *(const ushort4*)(X + (size_t)row * DD + c);
        float4 m;
        m.x = fmaxf(h2f(xu.x) * a.x + b.x, 0.f);
        m.y = fmaxf(h2f(xu.y) * a.y + b.y, 0.f);
        m.z = fmaxf(h2f(xu.z) * a.z + b.z, 0.f);
        m.w = fmaxf(h2f(xu.w) * a.w + b.w, 0.f);
        s.x += m.x; s.y += m.y; s.z += m.z; s.w += m.w;
        s2.x += m.x*m.x; s2.y += m.y*m.y; s2.z += m.z*m.z; s2.w += m.w*m.w;
    }
    sA[t] = s; sB[t] = s2;
    __syncthreads();
    if (t < 128) {
        sA[t].x += sA[t+128].x; sA[t].y += sA[t+128].y; sA[t].z += sA[t+128].z; sA[t].w += sA[t+128].w;
        sB[t].x += sB[t+128].x; sB[t].y += sB[t+128].y; sB[t].z += sB[t+128].z; sB[t].w += sB[t+128].w;
    }
    __syncthreads();
    if (t < 64) {
        float4 fs, fs2;
        fs.x = sA[t].x + sA[t+64].x; fs.y = sA[t].y + sA[t+64].y;
        fs.z = sA[t].z + sA[t+64].z; fs.w = sA[t].w + sA[t+64].w;
        fs2.x = sB[t].x + sB[t+64].x; fs2.y = sB[t].y + sB[t+64].y;
        fs2.z = sB[t].z + sB[t+64].z; fs2.w = sB[t].w + sB[t+64].w;
        atomicAdd(&sums3[c + 0], fs.x);  atomicAdd(&sums3[c + 1], fs.y);
        atomicAdd(&sums3[c + 2], fs.z);  atomicAdd(&sums3[c + 3], fs.w);
        atomicAdd(&sums3[DD + c + 0], fs2.x); atomicAdd(&sums3[DD + c + 1], fs2.y);
        atomicAdd(&sums3[DD + c + 2], fs2.z); atomicAdd(&sums3[DD + c + 3], fs2.w);
    }
}

// ---- final: h = relu(BN3(relu(BN2(t2)))); BN2/BN3 inline fin; write out + h16 ----
__global__ void final_k(const unsigned short* __restrict__ T2,
                        const float* __restrict__ sums2,
                        const float* __restrict__ g2, const float* __restrict__ bb2,
                        const float* __restrict__ sums3,
                        const float* __restrict__ g3, const float* __restrict__ bb3,
                        float4* __restrict__ Out, unsigned short* __restrict__ h16,
                        int loff4) {
    __shared__ float sc2_l[DD], sh2_l[DD], sc3_l[DD], sh3_l[DD];
    int t = threadIdx.x;
    if (t < DD) {
        float s = sums2[t], s2v = sums2[DD + t];
        float mu  = s * (1.f / NN);
        float var = s2v * (1.f / NN) - mu * mu;
        float a = rsqrtf(var + 1e-5f) * g2[t];
        sc2_l[t] = a;
        sh2_l[t] = bb2[t] - mu * a;
        s = sums3[t]; s2v = sums3[DD + t];
        mu  = s * (1.f / NN);
        var = s2v * (1.f / NN) - mu * mu;
        a = rsqrtf(var + 1e-5f) * g3[t];
        sc3_l[t] = a;
        sh3_l[t] = bb3[t] - mu * a;
    }
    __syncthreads();
    int i = blockIdx.x * 256 + t;             // over NN*64
    int row = i >> 6, c4 = i & 63;
    int c = c4 * 4;
    ushort4 xu = *(const ushort4*)(T2 + (size_t)i * 4);
    float4 a2 = *(const float4*)(sc2_l + c), b2 = *(const float4*)(sh2_l + c);
    float4 a3 = *(const float4*)(sc3_l + c), b3 = *(const float4*)(sh3_l + c);
    float4 m, h;
    m.x = fmaxf(h2f(xu.x) * a2.x + b2.x, 0.f);
    m.y = fmaxf(h2f(xu.y) * a2.y + b2.y, 0.f);
    m.z = fmaxf(h2f(xu.z) * a2.z + b2.z, 0.f);
    m.w = fmaxf(h2f(xu.w) * a2.w + b2.w, 0.f);
    h.x = fmaxf(m.x * a3.x + b3.x, 0.f);
    h.y = fmaxf(m.y * a3.y + b3.y, 0.f);
    h.z = fmaxf(m.z * a3.z + b3.z, 0.f);
    h.w = fmaxf(m.w * a3.w + b3.w, 0.f);
    Out[(size_t)row * 256 + loff4 + c4] = h;
    ushort4 u;
    u.x = f2h(h.x); u.y = f2h(h.y); u.z = f2h(h.z); u.w = f2h(h.w);
    *(ushort4*)(h16 + (size_t)i * 4) = u;
}

extern "C" void kernel_launch(void* const* d_in, const int* in_sizes, int n_in,
                              void* d_out, int out_size, void* d_ws, size_t ws_size,
                              hipStream_t stream) {
    const float* h_in = (const float*)d_in[0];
    const int*   ei   = (const int*)d_in[1];
    const float* W1   = (const float*)d_in[2];
    const float* b1   = (const float*)d_in[3];
    const float* W2   = (const float*)d_in[4];
    const float* b2   = (const float*)d_in[5];
    const float* g1   = (const float*)d_in[6];
    const float* bb1  = (const float*)d_in[7];
    const float* g2   = (const float*)d_in[8];
    const float* bb2  = (const float*)d_in[9];
    const float* g3   = (const float*)d_in[10];
    const float* bb3  = (const float*)d_in[11];
    float* out = (float*)d_out;

    const size_t SZ = (size_t)NN * DD;
    unsigned short* t1  = (unsigned short*)d_ws;               // NN*DD fp16
    unsigned short* t2  = t1 + SZ;                             // NN*DD fp16
    unsigned short* rb  = t2 + SZ;                             // NPAD*DD fp16
    unsigned short* h16 = rb + (size_t)NPAD * DD;              // NN*DD fp16
    unsigned short* Wt1 = h16 + SZ;
    unsigned short* Wt2 = Wt1 + (size_t)NL * DD * DD;
    float* sums_all = (float*)(Wt2 + (size_t)NL * DD * DD);    // 12*512 floats
    int* deg    = (int*)(sums_all + NL * 3 * 512);
    int* bsum   = deg + NN;          // 196 (pad 256)
    int* boff   = bsum + 256;        // 256
    int* rowptr = boff + 256;        // NN+1
    int* cursor = rowptr + NN + 1;   // NN
    int* csr    = cursor + NN;       // NE

    // one-time setup
    zeroall_k<<<196, 256, 0, stream>>>(sums_all, deg);
    wconv_k<<<1024, 256, 0, stream>>>(W1, Wt1);
    wconv_k<<<1024, 256, 0, stream>>>(W2, Wt2);
    h16conv_k<<<12500, 256, 0, stream>>>((const float4*)h_in, h16);
    hist_k<<<(NE + 255) / 256, 256, 0, stream>>>(ei, deg);
    bsum_k<<<196, 256, 0, stream>>>(deg, bsum);
    bscan_k<<<1, 256, 0, stream>>>(bsum, boff);
    rowptr_k<<<196, 256, 0, stream>>>(deg, boff, rowptr, cursor);
    fill_k<<<(NE + 255) / 256, 256, 0, stream>>>(ei, cursor, csr);

    for (int i = 0; i < NL; ++i) {
        float* sums1 = sums_all + (size_t)i * 1536;
        float* sums2 = sums1 + 512;
        float* sums3 = sums2 + 512;
        const size_t po = (size_t)i * DD;

        gather_k<<<NPAD / 4, 256, 0, stream>>>(rowptr, csr, h16, rb);

        gemm_f16_k<<<dim3(NPAD / 128, 2), 256, 0, stream>>>(
            rb, Wt1 + (size_t)i * DD * DD, b1 + po, t1, sums1);

        gemm_bn_k<<<dim3(NPAD / 128, 2), 256, 0, stream>>>(
            t1, Wt2 + (size_t)i * DD * DD, b2 + po, sums1, g1 + po, bb1 + po, t2, sums2);

        bn_stats_k<<<500, 256, 0, stream>>>(t2, sums2, g2 + po, bb2 + po, sums3);

        final_k<<<12500, 256, 0, stream>>>(t2, sums2, g2 + po, bb2 + po,
                                           sums3, g3 + po, bb3 + po,
                                           (float4*)out, h16, i * 64);
    }
}

// Round 12
// 967.972 us; speedup vs baseline: 1.0972x; 1.0972x over previous
//
#include <hip/hip_runtime.h>
#include <stdint.h>

#define NN 50000
#define NPAD 50048          // 391*128
#define NE 800000
#define DD 256
#define NL 4

typedef __attribute__((ext_vector_type(8))) _Float16 half8;
typedef __attribute__((ext_vector_type(4))) float f32x4;
typedef __attribute__((ext_vector_type(8))) float f32x8;
typedef __attribute__((ext_vector_type(8))) unsigned short ushort8_t;

__device__ inline unsigned short f2h(float x) {
    union { _Float16 h; unsigned short u; } v;
    v.h = (_Float16)x;
    return v.u;
}
__device__ inline float h2f(unsigned short u) {
    union { unsigned short u; _Float16 h; } v;
    v.u = u;
    return (float)v.h;
}

// ---- zero all sums buffers (12x512) + deg ----
__global__ void zeroall_k(float* __restrict__ sums, int* __restrict__ deg) {
    int i = blockIdx.x * 256 + threadIdx.x;
    if (i < NL * 3 * 512) sums[i] = 0.f;
    if (i < NN) deg[i] = 0;
}

// ---- convert W [L][K][N] fp32 -> Wt [L][N][K] fp16 ----
__global__ void wconv_k(const float* __restrict__ W, unsigned short* __restrict__ Wt) {
    int idx = blockIdx.x * 256 + threadIdx.x;
    int l   = idx >> 16;
    int rem = idx & 0xFFFF;
    int k   = rem >> 8;
    int n   = rem & 255;
    float x = W[(l << 16) + (k << 8) + n];
    Wt[(l << 16) + (n << 8) + k] = f2h(x);
}

// ---- convert h_in fp32 -> h16 fp16 (layer 0 only) ----
__global__ void h16conv_k(const float4* __restrict__ H, unsigned short* __restrict__ h16) {
    int i = blockIdx.x * 256 + threadIdx.x;    // over NN*64
    float4 v = H[i];
    ushort4 u;
    u.x = f2h(v.x); u.y = f2h(v.y); u.z = f2h(v.z); u.w = f2h(v.w);
    *(ushort4*)(h16 + (size_t)i * 4) = u;
}

// ======================= CSR build (once) =======================
__global__ void hist_k(const int* __restrict__ ei, int* __restrict__ deg) {
    int e = blockIdx.x * 256 + threadIdx.x;
    if (e < NE) atomicAdd(&deg[ei[NE + e]], 1);
}

__global__ void bsum_k(const int* __restrict__ deg, int* __restrict__ bsum) {
    __shared__ int sm[256];
    int i = blockIdx.x * 256 + threadIdx.x;
    sm[threadIdx.x] = (i < NN) ? deg[i] : 0;
    __syncthreads();
    for (int off = 128; off > 0; off >>= 1) {
        if (threadIdx.x < off) sm[threadIdx.x] += sm[threadIdx.x + off];
        __syncthreads();
    }
    if (threadIdx.x == 0) bsum[blockIdx.x] = sm[0];
}

__global__ void bscan_k(const int* __restrict__ bsum, int* __restrict__ boff) {
    __shared__ int sm[256];
    int t = threadIdx.x;
    int v = (t < 196) ? bsum[t] : 0;
    sm[t] = v; __syncthreads();
    for (int off = 1; off < 256; off <<= 1) {
        int u = (t >= off) ? sm[t - off] : 0;
        __syncthreads();
        sm[t] += u;
        __syncthreads();
    }
    boff[t] = sm[t] - v;
}

__global__ void rowptr_k(const int* __restrict__ deg, const int* __restrict__ boff,
                         int* __restrict__ rowptr, int* __restrict__ cursor) {
    __shared__ int sm[256];
    int b = blockIdx.x, t = threadIdx.x;
    int i = b * 256 + t;
    int v = (i < NN) ? deg[i] : 0;
    sm[t] = v; __syncthreads();
    for (int off = 1; off < 256; off <<= 1) {
        int u = (t >= off) ? sm[t - off] : 0;
        __syncthreads();
        sm[t] += u;
        __syncthreads();
    }
    int excl = boff[b] + sm[t] - v;
    if (i < NN) { rowptr[i] = excl; cursor[i] = excl; }
    if (i == NN - 1) rowptr[NN] = excl + v;
}

__global__ void fill_k(const int* __restrict__ ei, int* __restrict__ cursor,
                       int* __restrict__ csr) {
    int e = blockIdx.x * 256 + threadIdx.x;
    if (e < NE) {
        int d = ei[NE + e];
        int p = atomicAdd(&cursor[d], 1);
        csr[p] = ei[e];
    }
}

// ========== per-layer gather (fp16, deep-ILP: 8 outstanding loads/half) ==========
__global__ void gather_k(const int* __restrict__ rowptr, const int* __restrict__ csr,
                         const unsigned short* __restrict__ h16,
                         unsigned short* __restrict__ rb) {
    int w    = threadIdx.x >> 6;
    int lane = threadIdx.x & 63;
    int node = blockIdx.x * 4 + w;
    if (node >= NPAD) return;
    int half = lane >> 5;
    int l32  = lane & 31;
    int c    = l32 * 8;
    unsigned short* dst = rb + (size_t)node * DD + c;
    if (node >= NN) {
        if (half == 0) {
            ushort8_t z = {0,0,0,0,0,0,0,0};
            *(ushort8_t*)dst = z;
        }
        return;
    }
    int beg = rowptr[node], end = rowptr[node + 1];
    f32x8 acc = {0.f,0.f,0.f,0.f,0.f,0.f,0.f,0.f};
    if (half == 0) {
        ushort8_t hv = *(const ushort8_t*)(h16 + (size_t)node * DD + c);
        #pragma unroll
        for (int k = 0; k < 8; ++k) acc[k] = h2f(hv[k]);
    }
    int j = beg;
    // deep window: 16 neighbors/step, 8 loads in flight per half
    for (; j + 16 <= end; j += 16) {
        int i0 = csr[j + half],      i1 = csr[j + 2 + half];
        int i2 = csr[j + 4 + half],  i3 = csr[j + 6 + half];
        int i4 = csr[j + 8 + half],  i5 = csr[j + 10 + half];
        int i6 = csr[j + 12 + half], i7 = csr[j + 14 + half];
        ushort8_t v0 = *(const ushort8_t*)(h16 + (size_t)i0 * DD + c);
        ushort8_t v1 = *(const ushort8_t*)(h16 + (size_t)i1 * DD + c);
        ushort8_t v2 = *(const ushort8_t*)(h16 + (size_t)i2 * DD + c);
        ushort8_t v3 = *(const ushort8_t*)(h16 + (size_t)i3 * DD + c);
        ushort8_t v4 = *(const ushort8_t*)(h16 + (size_t)i4 * DD + c);
        ushort8_t v5 = *(const ushort8_t*)(h16 + (size_t)i5 * DD + c);
        ushort8_t v6 = *(const ushort8_t*)(h16 + (size_t)i6 * DD + c);
        ushort8_t v7 = *(const ushort8_t*)(h16 + (size_t)i7 * DD + c);
        #pragma unroll
        for (int k = 0; k < 8; ++k)
            acc[k] += ((h2f(v0[k]) + h2f(v1[k])) + (h2f(v2[k]) + h2f(v3[k])))
                    + ((h2f(v4[k]) + h2f(v5[k])) + (h2f(v6[k]) + h2f(v7[k])));
    }
    for (; j + 8 <= end; j += 8) {
        int i0 = csr[j + half],     i1 = csr[j + 2 + half];
        int i2 = csr[j + 4 + half], i3 = csr[j + 6 + half];
        ushort8_t v0 = *(const ushort8_t*)(h16 + (size_t)i0 * DD + c);
        ushort8_t v1 = *(const ushort8_t*)(h16 + (size_t)i1 * DD + c);
        ushort8_t v2 = *(const ushort8_t*)(h16 + (size_t)i2 * DD + c);
        ushort8_t v3 = *(const ushort8_t*)(h16 + (size_t)i3 * DD + c);
        #pragma unroll
        for (int k = 0; k < 8; ++k)
            acc[k] += (h2f(v0[k]) + h2f(v1[k])) + (h2f(v2[k]) + h2f(v3[k]));
    }
    for (; j + 2 <= end; j += 2) {
        int jj = csr[j + half];
        ushort8_t v0 = *(const ushort8_t*)(h16 + (size_t)jj * DD + c);
        #pragma unroll
        for (int k = 0; k < 8; ++k) acc[k] += h2f(v0[k]);
    }
    if (j < end && half == 0) {
        int jj = csr[j];
        ushort8_t v0 = *(const ushort8_t*)(h16 + (size_t)jj * DD + c);
        #pragma unroll
        for (int k = 0; k < 8; ++k) acc[k] += h2f(v0[k]);
    }
    #pragma unroll
    for (int k = 0; k < 8; ++k) acc[k] += __shfl_xor(acc[k], 32);
    if (half == 0) {
        ushort8_t u;
        #pragma unroll
        for (int k = 0; k < 8; ++k) u[k] = f2h(acc[k]);
        *(ushort8_t*)dst = u;
    }
}

// =================== GEMM 128x256 tile, 8 waves (2x4), BK=32, fp16 MFMA (R7) ===================
#define GEMM_EPILOGUE(CPTR, SUMS)                                                \
    _Pragma("unroll")                                                            \
    for (int nf = 0; nf < 4; ++nf) {                                             \
        int col = wc * 64 + nf * 16 + l15;                                       \
        float bs = bias[col];                                                    \
        float s = 0.f, s2 = 0.f;                                                 \
        _Pragma("unroll")                                                        \
        for (int mf = 0; mf < 4; ++mf) {                                         \
            int r0 = mbase + wr * 64 + mf * 16 + l4 * 4;                         \
            _Pragma("unroll")                                                    \
            for (int j = 0; j < 4; ++j) {                                        \
                int row = r0 + j;                                                \
                if (row < NN) {                                                  \
                    float cv = acc[mf][nf][j] + bs;                              \
                    CPTR[(size_t)row * DD + col] = f2h(cv);                      \
                    s += cv; s2 += cv * cv;                                      \
                }                                                                \
            }                                                                    \
        }                                                                        \
        s  += __shfl_xor(s, 16);  s  += __shfl_xor(s, 32);                       \
        s2 += __shfl_xor(s2, 16); s2 += __shfl_xor(s2, 32);                      \
        if (l4 == 0) {                                                           \
            atomicAdd(&SUMS[col], s);                                            \
            atomicAdd(&SUMS[DD + col], s2);                                      \
        }                                                                        \
    }

#define GEMM_MFMA_STEP()                                                         \
    {                                                                            \
        half8 af[4], bf[4];                                                      \
        _Pragma("unroll")                                                        \
        for (int mf = 0; mf < 4; ++mf)                                           \
            af[mf] = *(const half8*)&As[wr * 64 + mf * 16 + l15][l4 * 8];        \
        _Pragma("unroll")                                                        \
        for (int nf = 0; nf < 4; ++nf)                                           \
            bf[nf] = *(const half8*)&Bs[wc * 64 + nf * 16 + l15][l4 * 8];        \
        _Pragma("unroll")                                                        \
        for (int mf = 0; mf < 4; ++mf)                                           \
            _Pragma("unroll")                                                    \
            for (int nf = 0; nf < 4; ++nf)                                       \
                acc[mf][nf] = __builtin_amdgcn_mfma_f32_16x16x32_f16(            \
                    af[mf], bf[nf], acc[mf][nf], 0, 0, 0);                       \
    }

// GEMM1: A fp16 (rb, zero-padded rows), t1 = A @ Wt^T + b ; stats -> sums1
__global__ void gemm_f16_k(const unsigned short* __restrict__ A,
                           const unsigned short* __restrict__ Wt,
                           const float* __restrict__ bias,
                           unsigned short* __restrict__ C, float* __restrict__ sums1) {
    __shared__ unsigned short As[128][40];
    __shared__ unsigned short Bs[256][40];
    const int tid   = threadIdx.x;
    const int mbase = blockIdx.x * 128;
    const int wave  = tid >> 6, lane = tid & 63;
    const int wr = wave >> 2, wc = wave & 3;
    const int l15 = lane & 15, l4 = lane >> 4;

    f32x4 acc[4][4] = {};

    for (int ks = 0; ks < 8; ++ks) {
        const int k0 = ks * 32;
        {
            int row = tid >> 2, seg = (tid & 3) * 8;
            uint4 wv = *(const uint4*)(A + (size_t)(mbase + row) * DD + k0 + seg);
            *(uint4*)&As[row][seg] = wv;
        }
        #pragma unroll
        for (int sI = 0; sI < 2; ++sI) {
            int q = sI * 512 + tid;
            int col = q >> 2, seg = (q & 3) * 8;
            uint4 wv = *(const uint4*)(Wt + (size_t)col * DD + k0 + seg);
            *(uint4*)&Bs[col][seg] = wv;
        }
        __syncthreads();
        GEMM_MFMA_STEP()
        __syncthreads();
    }
    GEMM_EPILOGUE(C, sums1)
}

// GEMM2: A fp16 (t1); BN1 (inline fin from sums1) + ReLU at staging; stats -> sums2
__global__ void gemm_bn_k(const unsigned short* __restrict__ A,
                          const unsigned short* __restrict__ Wt,
                          const float* __restrict__ bias,
                          const float* __restrict__ sums1,
                          const float* __restrict__ g1, const float* __restrict__ bb1,
                          unsigned short* __restrict__ C, float* __restrict__ sums2) {
    __shared__ unsigned short As[128][40];
    __shared__ unsigned short Bs[256][40];
    __shared__ float sc_l[DD], sh_l[DD];
    const int tid   = threadIdx.x;
    const int mbase = blockIdx.x * 128;
    const int wave  = tid >> 6, lane = tid & 63;
    const int wr = wave >> 2, wc = wave & 3;
    const int l15 = lane & 15, l4 = lane >> 4;

    // inline fin1
    if (tid < DD) {
        float s = sums1[tid], s2 = sums1[DD + tid];
        float mu  = s * (1.f / NN);
        float var = s2 * (1.f / NN) - mu * mu;
        float a = rsqrtf(var + 1e-5f) * g1[tid];
        sc_l[tid] = a;
        sh_l[tid] = bb1[tid] - mu * a;
    }

    f32x4 acc[4][4] = {};

    for (int ks = 0; ks < 8; ++ks) {
        const int k0 = ks * 32;
        if (ks == 0) __syncthreads();   // sc_l/sh_l ready
        {
            int row = tid >> 2, seg = (tid & 3) * 8;
            int grow = mbase + row;
            uint4 wv = {0u, 0u, 0u, 0u};
            if (grow < NN) wv = *(const uint4*)(A + (size_t)grow * DD + k0 + seg);
            unsigned short* ph = (unsigned short*)&wv;
            int cb = k0 + seg;
            ushort4 u0, u1;
            u0.x = f2h(fmaxf(h2f(ph[0]) * sc_l[cb+0] + sh_l[cb+0], 0.f));
            u0.y = f2h(fmaxf(h2f(ph[1]) * sc_l[cb+1] + sh_l[cb+1], 0.f));
            u0.z = f2h(fmaxf(h2f(ph[2]) * sc_l[cb+2] + sh_l[cb+2], 0.f));
            u0.w = f2h(fmaxf(h2f(ph[3]) * sc_l[cb+3] + sh_l[cb+3], 0.f));
            u1.x = f2h(fmaxf(h2f(ph[4]) * sc_l[cb+4] + sh_l[cb+4], 0.f));
            u1.y = f2h(fmaxf(h2f(ph[5]) * sc_l[cb+5] + sh_l[cb+5], 0.f));
            u1.z = f2h(fmaxf(h2f(ph[6]) * sc_l[cb+6] + sh_l[cb+6], 0.f));
            u1.w = f2h(fmaxf(h2f(ph[7]) * sc_l[cb+7] + sh_l[cb+7], 0.f));
            *(ushort4*)&As[row][seg] = u0;
            *(ushort4*)&As[row][seg + 4] = u1;
        }
        #pragma unroll
        for (int sI = 0; sI < 2; ++sI) {
            int q = sI * 512 + tid;
            int col = q >> 2, seg = (q & 3) * 8;
            uint4 wv = *(const uint4*)(Wt + (size_t)col * DD + k0 + seg);
            *(uint4*)&Bs[col][seg] = wv;
        }
        __syncthreads();
        GEMM_MFMA_STEP()
        __syncthreads();
    }
    GEMM_EPILOGUE(C, sums2)
}

// ---- BN3 stats over m = relu(BN2(t2)); BN2 inline fin from sums2; stats -> sums3 ----
__global__ void bn_stats_k(const unsigned short* __restrict__ X,
                           const float* __restrict__ sums2,
                           const float* __restrict__ g2, const float* __restrict__ bb2,
                           float* __restrict__ sums3) {
    __shared__ float4 sA[256];
    __shared__ float4 sB[256];
    __shared__ float sc_l[DD], sh_l[DD];
    int t  = threadIdx.x;
    if (t < DD) {
        float s = sums2[t], s2v = sums2[DD + t];
        float mu  = s * (1.f / NN);
        float var = s2v * (1.f / NN) - mu * mu;
        float a = rsqrtf(var + 1e-5f) * g2[t];
        sc_l[t] = a;
        sh_l[t] = bb2[t] - mu * a;
    }
    __syncthreads();
    int rs = t >> 6;
    int c4 = t & 63;
    int c  = c4 * 4;
    float4 a = *(const float4*)(sc_l + c), b = *(const float4*)(sh_l + c);
    float4 s = {0.f,0.f,0.f,0.f}, s2 = {0.f,0.f,0.f,0.f};
    for (int r4 = blockIdx.x; r4 < NN / 4; r4 += gridDim.x) {
        int row = r4 * 4 + rs;
        ushort4 xu = *(const ushort4*)(X + (size_t)row * DD + c);
        float4 m;
        m.x = fmaxf(h2f(xu.x) * a.x + b.x, 0.f);
        m.y = fmaxf(h2f(xu.y) * a.y + b.y, 0.f);
        m.z = fmaxf(h2f(xu.z) * a.z + b.z, 0.f);
        m.w = fmaxf(h2f(xu.w) * a.w + b.w, 0.f);
        s.x += m.x; s.y += m.y; s.z += m.z; s.w += m.w;
        s2.x += m.x*m.x; s2.y += m.y*m.y; s2.z += m.z*m.z; s2.w += m.w*m.w;
    }
    sA[t] = s; sB[t] = s2;
    __syncthreads();
    if (t < 128) {
        sA[t].x += sA[t+128].x; sA[t].y += sA[t+128].y; sA[t].z += sA[t+128].z; sA[t].w += sA[t+128].w;
        sB[t].x += sB[t+128].x; sB[t].y += sB[t+128].y; sB[t].z += sB[t+128].z; sB[t].w += sB[t+128].w;
    }
    __syncthreads();
    if (t < 64) {
        float4 fs, fs2;
        fs.x = sA[t].x + sA[t+64].x; fs.y = sA[t].y + sA[t+64].y;
        fs.z = sA[t].z + sA[t+64].z; fs.w = sA[t].w + sA[t+64].w;
        fs2.x = sB[t].x + sB[t+64].x; fs2.y = sB[t].y + sB[t+64].y;
        fs2.z = sB[t].z + sB[t+64].z; fs2.w = sB[t].w + sB[t+64].w;
        atomicAdd(&sums3[c + 0], fs.x);  atomicAdd(&sums3[c + 1], fs.y);
        atomicAdd(&sums3[c + 2], fs.z);  atomicAdd(&sums3[c + 3], fs.w);
        atomicAdd(&sums3[DD + c + 0], fs2.x); atomicAdd(&sums3[DD + c + 1], fs2.y);
        atomicAdd(&sums3[DD + c + 2], fs2.z); atomicAdd(&sums3[DD + c + 3], fs2.w);
    }
}

// ---- final: h = relu(BN3(relu(BN2(t2)))); BN2/BN3 inline fin; write out + h16 ----
__global__ void final_k(const unsigned short* __restrict__ T2,
                        const float* __restrict__ sums2,
                        const float* __restrict__ g2, const float* __restrict__ bb2,
                        const float* __restrict__ sums3,
                        const float* __restrict__ g3, const float* __restrict__ bb3,
                        float4* __restrict__ Out, unsigned short* __restrict__ h16,
                        int loff4) {
    __shared__ float sc2_l[DD], sh2_l[DD], sc3_l[DD], sh3_l[DD];
    int t = threadIdx.x;
    if (t < DD) {
        float s = sums2[t], s2v = sums2[DD + t];
        float mu  = s * (1.f / NN);
        float var = s2v * (1.f / NN) - mu * mu;
        float a = rsqrtf(var + 1e-5f) * g2[t];
        sc2_l[t] = a;
        sh2_l[t] = bb2[t] - mu * a;
        s = sums3[t]; s2v = sums3[DD + t];
        mu  = s * (1.f / NN);
        var = s2v * (1.f / NN) - mu * mu;
        a = rsqrtf(var + 1e-5f) * g3[t];
        sc3_l[t] = a;
        sh3_l[t] = bb3[t] - mu * a;
    }
    __syncthreads();
    int i = blockIdx.x * 256 + t;             // over NN*64
    int row = i >> 6, c4 = i & 63;
    int c = c4 * 4;
    ushort4 xu = *(const ushort4*)(T2 + (size_t)i * 4);
    float4 a2 = *(const float4*)(sc2_l + c), b2 = *(const float4*)(sh2_l + c);
    float4 a3 = *(const float4*)(sc3_l + c), b3 = *(const float4*)(sh3_l + c);
    float4 m, h;
    m.x = fmaxf(h2f(xu.x) * a2.x + b2.x, 0.f);
    m.y = fmaxf(h2f(xu.y) * a2.y + b2.y, 0.f);
    m.z = fmaxf(h2f(xu.z) * a2.z + b2.z, 0.f);
    m.w = fmaxf(h2f(xu.w) * a2.w + b2.w, 0.f);
    h.x = fmaxf(m.x * a3.x + b3.x, 0.f);
    h.y = fmaxf(m.y * a3.y + b3.y, 0.f);
    h.z = fmaxf(m.z * a3.z + b3.z, 0.f);
    h.w = fmaxf(m.w * a3.w + b3.w, 0.f);
    Out[(size_t)row * 256 + loff4 + c4] = h;
    ushort4 u;
    u.x = f2h(h.x); u.y = f2h(h.y); u.z = f2h(h.z); u.w = f2h(h.w);
    *(ushort4*)(h16 + (size_t)i * 4) = u;
}

extern "C" void kernel_launch(void* const* d_in, const int* in_sizes, int n_in,
                              void* d_out, int out_size, void* d_ws, size_t ws_size,
                              hipStream_t stream) {
    const float* h_in = (const float*)d_in[0];
    const int*   ei   = (const int*)d_in[1];
    const float* W1   = (const float*)d_in[2];
    const float* b1   = (const float*)d_in[3];
    const float* W2   = (const float*)d_in[4];
    const float* b2   = (const float*)d_in[5];
    const float* g1   = (const float*)d_in[6];
    const float* bb1  = (const float*)d_in[7];
    const float* g2   = (const float*)d_in[8];
    const float* bb2  = (const float*)d_in[9];
    const float* g3   = (const float*)d_in[10];
    const float* bb3  = (const float*)d_in[11];
    float* out = (float*)d_out;

    const size_t SZ = (size_t)NN * DD;
    unsigned short* t1  = (unsigned short*)d_ws;               // NN*DD fp16
    unsigned short* t2  = t1 + SZ;                             // NN*DD fp16
    unsigned short* rb  = t2 + SZ;                             // NPAD*DD fp16
    unsigned short* h16 = rb + (size_t)NPAD * DD;              // NN*DD fp16
    unsigned short* Wt1 = h16 + SZ;
    unsigned short* Wt2 = Wt1 + (size_t)NL * DD * DD;
    float* sums_all = (float*)(Wt2 + (size_t)NL * DD * DD);    // 12*512 floats
    int* deg    = (int*)(sums_all + NL * 3 * 512);
    int* bsum   = deg + NN;          // 196 (pad 256)
    int* boff   = bsum + 256;        // 256
    int* rowptr = boff + 256;        // NN+1
    int* cursor = rowptr + NN + 1;   // NN
    int* csr    = cursor + NN;       // NE

    // one-time setup
    zeroall_k<<<196, 256, 0, stream>>>(sums_all, deg);
    wconv_k<<<1024, 256, 0, stream>>>(W1, Wt1);
    wconv_k<<<1024, 256, 0, stream>>>(W2, Wt2);
    h16conv_k<<<12500, 256, 0, stream>>>((const float4*)h_in, h16);
    hist_k<<<(NE + 255) / 256, 256, 0, stream>>>(ei, deg);
    bsum_k<<<196, 256, 0, stream>>>(deg, bsum);
    bscan_k<<<1, 256, 0, stream>>>(bsum, boff);
    rowptr_k<<<196, 256, 0, stream>>>(deg, boff, rowptr, cursor);
    fill_k<<<(NE + 255) / 256, 256, 0, stream>>>(ei, cursor, csr);

    for (int i = 0; i < NL; ++i) {
        float* sums1 = sums_all + (size_t)i * 1536;
        float* sums2 = sums1 + 512;
        float* sums3 = sums2 + 512;
        const size_t po = (size_t)i * DD;

        gather_k<<<NPAD / 4, 256, 0, stream>>>(rowptr, csr, h16, rb);

        gemm_f16_k<<<NPAD / 128, 512, 0, stream>>>(
            rb, Wt1 + (size_t)i * DD * DD, b1 + po, t1, sums1);

        gemm_bn_k<<<NPAD / 128, 512, 0, stream>>>(
            t1, Wt2 + (size_t)i * DD * DD, b2 + po, sums1, g1 + po, bb1 + po, t2, sums2);

        bn_stats_k<<<500, 256, 0, stream>>>(t2, sums2, g2 + po, bb2 + po, sums3);

        final_k<<<12500, 256, 0, stream>>>(t2, sums2, g2 + po, bb2 + po,
                                           sums3, g3 + po, bb3 + po,
                                           (float4*)out, h16, i * 64);
    }
}

// Round 13
// 962.271 us; speedup vs baseline: 1.1037x; 1.0059x over previous
//
#include <hip/hip_runtime.h>
#include <stdint.h>

#define NN 50000
#define NPAD 50048          // 391*128
#define NE 800000
#define DD 256
#define NL 4

typedef __attribute__((ext_vector_type(8))) _Float16 half8;
typedef __attribute__((ext_vector_type(4))) float f32x4;
typedef __attribute__((ext_vector_type(8))) float f32x8;
typedef __attribute__((ext_vector_type(8))) unsigned short ushort8_t;

__device__ inline unsigned short f2h(float x) {
    union { _Float16 h; unsigned short u; } v;
    v.h = (_Float16)x;
    return v.u;
}
__device__ inline float h2f(unsigned short u) {
    union { unsigned short u; _Float16 h; } v;
    v.u = u;
    return (float)v.h;
}

// async global->LDS, 16B per lane; lds base must be wave-uniform (HW: base + lane*16)
__device__ inline void gload16(const void* g, void* lds_base) {
    __builtin_amdgcn_global_load_lds(
        (const __attribute__((address_space(1))) void*)g,
        (__attribute__((address_space(3))) void*)lds_base,
        16, 0, 0);
}

// swizzled fragment read from linear [R][32]-fp16 LDS tile (64B rows, 4x16B chunks)
__device__ inline const half8* lds_frag(const unsigned short* base_lin, int row, int l4) {
    int chunk = l4 ^ ((row >> 1) & 3);
    return (const half8*)((const char*)base_lin + row * 64 + chunk * 16);
}

// ---- zero all sums buffers (12x512) + deg ----
__global__ void zeroall_k(float* __restrict__ sums, int* __restrict__ deg) {
    int i = blockIdx.x * 256 + threadIdx.x;
    if (i < NL * 3 * 512) sums[i] = 0.f;
    if (i < NN) deg[i] = 0;
}

// ---- convert W [L][K][N] fp32 -> Wt [L][N][K] fp16 ----
__global__ void wconv_k(const float* __restrict__ W, unsigned short* __restrict__ Wt) {
    int idx = blockIdx.x * 256 + threadIdx.x;
    int l   = idx >> 16;
    int rem = idx & 0xFFFF;
    int k   = rem >> 8;
    int n   = rem & 255;
    float x = W[(l << 16) + (k << 8) + n];
    Wt[(l << 16) + (n << 8) + k] = f2h(x);
}

// ---- convert h_in fp32 -> h16 fp16 (layer 0 only) ----
__global__ void h16conv_k(const float4* __restrict__ H, unsigned short* __restrict__ h16) {
    int i = blockIdx.x * 256 + threadIdx.x;    // over NN*64
    float4 v = H[i];
    ushort4 u;
    u.x = f2h(v.x); u.y = f2h(v.y); u.z = f2h(v.z); u.w = f2h(v.w);
    *(ushort4*)(h16 + (size_t)i * 4) = u;
}

// ======================= CSR build (once) =======================
__global__ void hist_k(const int* __restrict__ ei, int* __restrict__ deg) {
    int e = blockIdx.x * 256 + threadIdx.x;
    if (e < NE) atomicAdd(&deg[ei[NE + e]], 1);
}

__global__ void bsum_k(const int* __restrict__ deg, int* __restrict__ bsum) {
    __shared__ int sm[256];
    int i = blockIdx.x * 256 + threadIdx.x;
    sm[threadIdx.x] = (i < NN) ? deg[i] : 0;
    __syncthreads();
    for (int off = 128; off > 0; off >>= 1) {
        if (threadIdx.x < off) sm[threadIdx.x] += sm[threadIdx.x + off];
        __syncthreads();
    }
    if (threadIdx.x == 0) bsum[blockIdx.x] = sm[0];
}

__global__ void bscan_k(const int* __restrict__ bsum, int* __restrict__ boff) {
    __shared__ int sm[256];
    int t = threadIdx.x;
    int v = (t < 196) ? bsum[t] : 0;
    sm[t] = v; __syncthreads();
    for (int off = 1; off < 256; off <<= 1) {
        int u = (t >= off) ? sm[t - off] : 0;
        __syncthreads();
        sm[t] += u;
        __syncthreads();
    }
    boff[t] = sm[t] - v;
}

__global__ void rowptr_k(const int* __restrict__ deg, const int* __restrict__ boff,
                         int* __restrict__ rowptr, int* __restrict__ cursor) {
    __shared__ int sm[256];
    int b = blockIdx.x, t = threadIdx.x;
    int i = b * 256 + t;
    int v = (i < NN) ? deg[i] : 0;
    sm[t] = v; __syncthreads();
    for (int off = 1; off < 256; off <<= 1) {
        int u = (t >= off) ? sm[t - off] : 0;
        __syncthreads();
        sm[t] += u;
        __syncthreads();
    }
    int excl = boff[b] + sm[t] - v;
    if (i < NN) { rowptr[i] = excl; cursor[i] = excl; }
    if (i == NN - 1) rowptr[NN] = excl + v;
}

__global__ void fill_k(const int* __restrict__ ei, int* __restrict__ cursor,
                       int* __restrict__ csr) {
    int e = blockIdx.x * 256 + threadIdx.x;
    if (e < NE) {
        int d = ei[NE + e];
        int p = atomicAdd(&cursor[d], 1);
        csr[p] = ei[e];
    }
}

// ======================= per-layer gather (fp16, 2 rows/wave-step) =======================
__global__ void gather_k(const int* __restrict__ rowptr, const int* __restrict__ csr,
                         const unsigned short* __restrict__ h16,
                         unsigned short* __restrict__ rb) {
    int w    = threadIdx.x >> 6;
    int lane = threadIdx.x & 63;
    int node = blockIdx.x * 4 + w;
    if (node >= NPAD) return;
    int half = lane >> 5;
    int l32  = lane & 31;
    int c    = l32 * 8;
    unsigned short* dst = rb + (size_t)node * DD + c;
    if (node >= NN) {
        if (half == 0) {
            ushort8_t z = {0,0,0,0,0,0,0,0};
            *(ushort8_t*)dst = z;
        }
        return;
    }
    int beg = rowptr[node], end = rowptr[node + 1];
    f32x8 acc = {0.f,0.f,0.f,0.f,0.f,0.f,0.f,0.f};
    if (half == 0) {
        ushort8_t hv = *(const ushort8_t*)(h16 + (size_t)node * DD + c);
        #pragma unroll
        for (int k = 0; k < 8; ++k) acc[k] = h2f(hv[k]);
    }
    int j = beg;
    for (; j + 8 <= end; j += 8) {
        int j0 = csr[j + half], j1 = csr[j + 2 + half];
        int j2 = csr[j + 4 + half], j3 = csr[j + 6 + half];
        ushort8_t v0 = *(const ushort8_t*)(h16 + (size_t)j0 * DD + c);
        ushort8_t v1 = *(const ushort8_t*)(h16 + (size_t)j1 * DD + c);
        ushort8_t v2 = *(const ushort8_t*)(h16 + (size_t)j2 * DD + c);
        ushort8_t v3 = *(const ushort8_t*)(h16 + (size_t)j3 * DD + c);
        #pragma unroll
        for (int k = 0; k < 8; ++k)
            acc[k] += (h2f(v0[k]) + h2f(v1[k])) + (h2f(v2[k]) + h2f(v3[k]));
    }
    for (; j + 2 <= end; j += 2) {
        int jj = csr[j + half];
        ushort8_t v0 = *(const ushort8_t*)(h16 + (size_t)jj * DD + c);
        #pragma unroll
        for (int k = 0; k < 8; ++k) acc[k] += h2f(v0[k]);
    }
    if (j < end && half == 0) {
        int jj = csr[j];
        ushort8_t v0 = *(const ushort8_t*)(h16 + (size_t)jj * DD + c);
        #pragma unroll
        for (int k = 0; k < 8; ++k) acc[k] += h2f(v0[k]);
    }
    #pragma unroll
    for (int k = 0; k < 8; ++k) acc[k] += __shfl_xor(acc[k], 32);
    if (half == 0) {
        ushort8_t u;
        #pragma unroll
        for (int k = 0; k < 8; ++k) u[k] = f2h(acc[k]);
        *(ushort8_t*)dst = u;
    }
}

// =================== GEMM 128x256 tile, 8 waves (2x4), BK=32, fp16 MFMA ===================
#define GEMM_EPILOGUE(CPTR, SUMS)                                                \
    _Pragma("unroll")                                                            \
    for (int nf = 0; nf < 4; ++nf) {                                             \
        int col = wc * 64 + nf * 16 + l15;                                       \
        float bs = bias[col];                                                    \
        float s = 0.f, s2 = 0.f;                                                 \
        _Pragma("unroll")                                                        \
        for (int mf = 0; mf < 4; ++mf) {                                         \
            int r0 = mbase + wr * 64 + mf * 16 + l4 * 4;                         \
            _Pragma("unroll")                                                    \
            for (int j = 0; j < 4; ++j) {                                        \
                int row = r0 + j;                                                \
                if (row < NN) {                                                  \
                    float cv = acc[mf][nf][j] + bs;                              \
                    CPTR[(size_t)row * DD + col] = f2h(cv);                      \
                    s += cv; s2 += cv * cv;                                      \
                }                                                                \
            }                                                                    \
        }                                                                        \
        s  += __shfl_xor(s, 16);  s  += __shfl_xor(s, 32);                       \
        s2 += __shfl_xor(s2, 16); s2 += __shfl_xor(s2, 32);                      \
        if (l4 == 0) {                                                           \
            atomicAdd(&SUMS[col], s);                                            \
            atomicAdd(&SUMS[DD + col], s2);                                      \
        }                                                                        \
    }

// GEMM1: A fp16 (rb, zero-padded rows), t1 = A @ Wt^T + b ; stats -> sums1
// A and B staged via global_load_lds into linear LDS with chunk swizzle.
__global__ void gemm_f16_k(const unsigned short* __restrict__ A,
                           const unsigned short* __restrict__ Wt,
                           const float* __restrict__ bias,
                           unsigned short* __restrict__ C, float* __restrict__ sums1) {
    __shared__ unsigned short AsL[128 * 32];   // linear, 64B rows
    __shared__ unsigned short BsL[256 * 32];
    const int tid   = threadIdx.x;
    const int mbase = blockIdx.x * 128;
    const int wave  = tid >> 6, lane = tid & 63;
    const int wr = wave >> 2, wc = wave & 3;
    const int l15 = lane & 15, l4 = lane >> 4;

    f32x4 acc[4][4] = {};

    for (int ks = 0; ks < 8; ++ks) {
        const int k0 = ks * 32;
        // A: 512 chunks (128 rows x 4), one 16B chunk per thread
        {
            int q = tid;                    // 0..511
            int row = q >> 2, pc = q & 3;
            int gc = pc ^ ((row >> 1) & 3);
            gload16(A + (size_t)(mbase + row) * DD + k0 + gc * 8,
                    AsL + (size_t)wave * 64 * 8);
        }
        // B: 1024 chunks (256 rows x 4), two per thread
        #pragma unroll
        for (int p = 0; p < 2; ++p) {
            int q = p * 512 + tid;
            int row = q >> 2, pc = q & 3;
            int gc = pc ^ ((row >> 1) & 3);
            gload16(Wt + (size_t)row * DD + k0 + gc * 8,
                    BsL + ((size_t)p * 512 + (size_t)wave * 64) * 8);
        }
        __syncthreads();
        half8 af[4], bf[4];
        #pragma unroll
        for (int mf = 0; mf < 4; ++mf)
            af[mf] = *lds_frag(AsL, wr * 64 + mf * 16 + l15, l4);
        #pragma unroll
        for (int nf = 0; nf < 4; ++nf)
            bf[nf] = *lds_frag(BsL, wc * 64 + nf * 16 + l15, l4);
        #pragma unroll
        for (int mf = 0; mf < 4; ++mf)
            #pragma unroll
            for (int nf = 0; nf < 4; ++nf)
                acc[mf][nf] = __builtin_amdgcn_mfma_f32_16x16x32_f16(
                    af[mf], bf[nf], acc[mf][nf], 0, 0, 0);
        __syncthreads();
    }
    GEMM_EPILOGUE(C, sums1)
}

// GEMM2: A fp16 (t1); BN1 (inline fin from sums1) + ReLU at staging (padded LDS);
// B staged via global_load_lds (linear+swizzle); stats -> sums2
__global__ void gemm_bn_k(const unsigned short* __restrict__ A,
                          const unsigned short* __restrict__ Wt,
                          const float* __restrict__ bias,
                          const float* __restrict__ sums1,
                          const float* __restrict__ g1, const float* __restrict__ bb1,
                          unsigned short* __restrict__ C, float* __restrict__ sums2) {
    __shared__ unsigned short As[128][40];
    __shared__ unsigned short BsL[256 * 32];
    __shared__ float sc_l[DD], sh_l[DD];
    const int tid   = threadIdx.x;
    const int mbase = blockIdx.x * 128;
    const int wave  = tid >> 6, lane = tid & 63;
    const int wr = wave >> 2, wc = wave & 3;
    const int l15 = lane & 15, l4 = lane >> 4;

    // inline fin1
    if (tid < DD) {
        float s = sums1[tid], s2 = sums1[DD + tid];
        float mu  = s * (1.f / NN);
        float var = s2 * (1.f / NN) - mu * mu;
        float a = rsqrtf(var + 1e-5f) * g1[tid];
        sc_l[tid] = a;
        sh_l[tid] = bb1[tid] - mu * a;
    }

    f32x4 acc[4][4] = {};

    for (int ks = 0; ks < 8; ++ks) {
        const int k0 = ks * 32;
        if (ks == 0) __syncthreads();   // sc_l/sh_l ready
        // B first (async, no VGPR roundtrip)
        #pragma unroll
        for (int p = 0; p < 2; ++p) {
            int q = p * 512 + tid;
            int row = q >> 2, pc = q & 3;
            int gc = pc ^ ((row >> 1) & 3);
            gload16(Wt + (size_t)row * DD + k0 + gc * 8,
                    BsL + ((size_t)p * 512 + (size_t)wave * 64) * 8);
        }
        // A: fp16 -> BN+ReLU -> fp16 into padded LDS
        {
            int row = tid >> 2, seg = (tid & 3) * 8;
            int grow = mbase + row;
            uint4 wv = {0u, 0u, 0u, 0u};
            if (grow < NN) wv = *(const uint4*)(A + (size_t)grow * DD + k0 + seg);
            unsigned short* ph = (unsigned short*)&wv;
            int cb = k0 + seg;
            ushort4 u0, u1;
            u0.x = f2h(fmaxf(h2f(ph[0]) * sc_l[cb+0] + sh_l[cb+0], 0.f));
            u0.y = f2h(fmaxf(h2f(ph[1]) * sc_l[cb+1] + sh_l[cb+1], 0.f));
            u0.z = f2h(fmaxf(h2f(ph[2]) * sc_l[cb+2] + sh_l[cb+2], 0.f));
            u0.w = f2h(fmaxf(h2f(ph[3]) * sc_l[cb+3] + sh_l[cb+3], 0.f));
            u1.x = f2h(fmaxf(h2f(ph[4]) * sc_l[cb+4] + sh_l[cb+4], 0.f));
            u1.y = f2h(fmaxf(h2f(ph[5]) * sc_l[cb+5] + sh_l[cb+5], 0.f));
            u1.z = f2h(fmaxf(h2f(ph[6]) * sc_l[cb+6] + sh_l[cb+6], 0.f));
            u1.w = f2h(fmaxf(h2f(ph[7]) * sc_l[cb+7] + sh_l[cb+7], 0.f));
            *(ushort4*)&As[row][seg] = u0;
            *(ushort4*)&As[row][seg + 4] = u1;
        }
        __syncthreads();
        half8 af[4], bf[4];
        #pragma unroll
        for (int mf = 0; mf < 4; ++mf)
            af[mf] = *(const half8*)&As[wr * 64 + mf * 16 + l15][l4 * 8];
        #pragma unroll
        for (int nf = 0; nf < 4; ++nf)
            bf[nf] = *lds_frag(BsL, wc * 64 + nf * 16 + l15, l4);
        #pragma unroll
        for (int mf = 0; mf < 4; ++mf)
            #pragma unroll
            for (int nf = 0; nf < 4; ++nf)
                acc[mf][nf] = __builtin_amdgcn_mfma_f32_16x16x32_f16(
                    af[mf], bf[nf], acc[mf][nf], 0, 0, 0);
        __syncthreads();
    }
    GEMM_EPILOGUE(C, sums2)
}

// ---- BN3 stats over m = relu(BN2(t2)); BN2 inline fin from sums2; stats -> sums3 ----
__global__ void bn_stats_k(const unsigned short* __restrict__ X,
                           const float* __restrict__ sums2,
                           const float* __restrict__ g2, const float* __restrict__ bb2,
                           float* __restrict__ sums3) {
    __shared__ float4 sA[256];
    __shared__ float4 sB[256];
    __shared__ float sc_l[DD], sh_l[DD];
    int t  = threadIdx.x;
    if (t < DD) {
        float s = sums2[t], s2v = sums2[DD + t];
        float mu  = s * (1.f / NN);
        float var = s2v * (1.f / NN) - mu * mu;
        float a = rsqrtf(var + 1e-5f) * g2[t];
        sc_l[t] = a;
        sh_l[t] = bb2[t] - mu * a;
    }
    __syncthreads();
    int rs = t >> 6;
    int c4 = t & 63;
    int c  = c4 * 4;
    float4 a = *(const float4*)(sc_l + c), b = *(const float4*)(sh_l + c);
    float4 s = {0.f,0.f,0.f,0.f}, s2 = {0.f,0.f,0.f,0.f};
    for (int r4 = blockIdx.x; r4 < NN / 4; r4 += gridDim.x) {
        int row = r4 * 4 + rs;
        ushort4 xu = *(const ushort4*)(X + (size_t)row * DD + c);
        float4 m;
        m.x = fmaxf(h2f(xu.x) * a.x + b.x, 0.f);
        m.y = fmaxf(h2f(xu.y) * a.y + b.y, 0.f);
        m.z = fmaxf(h2f(xu.z) * a.z + b.z, 0.f);
        m.w = fmaxf(h2f(xu.w) * a.w + b.w, 0.f);
        s.x += m.x; s.y += m.y; s.z += m.z; s.w += m.w;
        s2.x += m.x*m.x; s2.y += m.y*m.y; s2.z += m.z*m.z; s2.w += m.w*m.w;
    }
    sA[t] = s; sB[t] = s2;
    __syncthreads();
    if (t < 128) {
        sA[t].x += sA[t+128].x; sA[t].y += sA[t+128].y; sA[t].z += sA[t+128].z; sA[t].w += sA[t+128].w;
        sB[t].x += sB[t+128].x; sB[t].y += sB[t+128].y; sB[t].z += sB[t+128].z; sB[t].w += sB[t+128].w;
    }
    __syncthreads();
    if (t < 64) {
        float4 fs, fs2;
        fs.x = sA[t].x + sA[t+64].x; fs.y = sA[t].y + sA[t+64].y;
        fs.z = sA[t].z + sA[t+64].z; fs.w = sA[t].w + sA[t+64].w;
        fs2.x = sB[t].x + sB[t+64].x; fs2.y = sB[t].y + sB[t+64].y;
        fs2.z = sB[t].z + sB[t+64].z; fs2.w = sB[t].w + sB[t+64].w;
        atomicAdd(&sums3[c + 0], fs.x);  atomicAdd(&sums3[c + 1], fs.y);
        atomicAdd(&sums3[c + 2], fs.z);  atomicAdd(&sums3[c + 3], fs.w);
        atomicAdd(&sums3[DD + c + 0], fs2.x); atomicAdd(&sums3[DD + c + 1], fs2.y);
        atomicAdd(&sums3[DD + c + 2], fs2.z); atomicAdd(&sums3[DD + c + 3], fs2.w);
    }
}

// ---- final: h = relu(BN3(relu(BN2(t2)))); BN2/BN3 inline fin; write out + h16 ----
__global__ void final_k(const unsigned short* __restrict__ T2,
                        const float* __restrict__ sums2,
                        const float* __restrict__ g2, const float* __restrict__ bb2,
                        const float* __restrict__ sums3,
                        const float* __restrict__ g3, const float* __restrict__ bb3,
                        float4* __restrict__ Out, unsigned short* __restrict__ h16,
                        int loff4) {
    __shared__ float sc2_l[DD], sh2_l[DD], sc3_l[DD], sh3_l[DD];
    int t = threadIdx.x;
    if (t < DD) {
        float s = sums2[t], s2v = sums2[DD + t];
        float mu  = s * (1.f / NN);
        float var = s2v * (1.f / NN) - mu * mu;
        float a = rsqrtf(var + 1e-5f) * g2[t];
        sc2_l[t] = a;
        sh2_l[t] = bb2[t] - mu * a;
        s = sums3[t]; s2v = sums3[DD + t];
        mu  = s * (1.f / NN);
        var = s2v * (1.f / NN) - mu * mu;
        a = rsqrtf(var + 1e-5f) * g3[t];
        sc3_l[t] = a;
        sh3_l[t] = bb3[t] - mu * a;
    }
    __syncthreads();
    int i = blockIdx.x * 256 + t;             // over NN*64
    int row = i >> 6, c4 = i & 63;
    int c = c4 * 4;
    ushort4 xu = *(const ushort4*)(T2 + (size_t)i * 4);
    float4 a2 = *(const float4*)(sc2_l + c), b2 = *(const float4*)(sh2_l + c);
    float4 a3 = *(const float4*)(sc3_l + c), b3 = *(const float4*)(sh3_l + c);
    float4 m, h;
    m.x = fmaxf(h2f(xu.x) * a2.x + b2.x, 0.f);
    m.y = fmaxf(h2f(xu.y) * a2.y + b2.y, 0.f);
    m.z = fmaxf(h2f(xu.z) * a2.z + b2.z, 0.f);
    m.w = fmaxf(h2f(xu.w) * a2.w + b2.w, 0.f);
    h.x = fmaxf(m.x * a3.x + b3.x, 0.f);
    h.y = fmaxf(m.y * a3.y + b3.y, 0.f);
    h.z = fmaxf(m.z * a3.z + b3.z, 0.f);
    h.w = fmaxf(m.w * a3.w + b3.w, 0.f);
    Out[(size_t)row * 256 + loff4 + c4] = h;
    ushort4 u;
    u.x = f2h(h.x); u.y = f2h(h.y); u.z = f2h(h.z); u.w = f2h(h.w);
    *(ushort4*)(h16 + (size_t)i * 4) = u;
}

extern "C" void kernel_launch(void* const* d_in, const int* in_sizes, int n_in,
                              void* d_out, int out_size, void* d_ws, size_t ws_size,
                              hipStream_t stream) {
    const float* h_in = (const float*)d_in[0];
    const int*   ei   = (const int*)d_in[1];
    const float* W1   = (const float*)d_in[2];
    const float* b1   = (const float*)d_in[3];
    const float* W2   = (const float*)d_in[4];
    const float* b2   = (const float*)d_in[5];
    const float* g1   = (const float*)d_in[6];
    const float* bb1  = (const float*)d_in[7];
    const float* g2   = (const float*)d_in[8];
    const float* bb2  = (const float*)d_in[9];
    const float* g3   = (const float*)d_in[10];
    const float* bb3  = (const float*)d_in[11];
    float* out = (float*)d_out;

    const size_t SZ = (size_t)NN * DD;
    unsigned short* t1  = (unsigned short*)d_ws;               // NN*DD fp16
    unsigned short* t2  = t1 + SZ;                             // NN*DD fp16
    unsigned short* rb  = t2 + SZ;                             // NPAD*DD fp16
    unsigned short* h16 = rb + (size_t)NPAD * DD;              // NN*DD fp16
    unsigned short* Wt1 = h16 + SZ;
    unsigned short* Wt2 = Wt1 + (size_t)NL * DD * DD;
    float* sums_all = (float*)(Wt2 + (size_t)NL * DD * DD);    // 12*512 floats
    int* deg    = (int*)(sums_all + NL * 3 * 512);
    int* bsum   = deg + NN;          // 196 (pad 256)
    int* boff   = bsum + 256;        // 256
    int* rowptr = boff + 256;        // NN+1
    int* cursor = rowptr + NN + 1;   // NN
    int* csr    = cursor + NN;       // NE

    // one-time setup
    zeroall_k<<<196, 256, 0, stream>>>(sums_all, deg);
    wconv_k<<<1024, 256, 0, stream>>>(W1, Wt1);
    wconv_k<<<1024, 256, 0, stream>>>(W2, Wt2);
    h16conv_k<<<12500, 256, 0, stream>>>((const float4*)h_in, h16);
    hist_k<<<(NE + 255) / 256, 256, 0, stream>>>(ei, deg);
    bsum_k<<<196, 256, 0, stream>>>(deg, bsum);
    bscan_k<<<1, 256, 0, stream>>>(bsum, boff);
    rowptr_k<<<196, 256, 0, stream>>>(deg, boff, rowptr, cursor);
    fill_k<<<(NE + 255) / 256, 256, 0, stream>>>(ei, cursor, csr);

    for (int i = 0; i < NL; ++i) {
        float* sums1 = sums_all + (size_t)i * 1536;
        float* sums2 = sums1 + 512;
        float* sums3 = sums2 + 512;
        const size_t po = (size_t)i * DD;

        gather_k<<<NPAD / 4, 256, 0, stream>>>(rowptr, csr, h16, rb);

        gemm_f16_k<<<NPAD / 128, 512, 0, stream>>>(
            rb, Wt1 + (size_t)i * DD * DD, b1 + po, t1, sums1);

        gemm_bn_k<<<NPAD / 128, 512, 0, stream>>>(
            t1, Wt2 + (size_t)i * DD * DD, b2 + po, sums1, g1 + po, bb1 + po, t2, sums2);

        bn_stats_k<<<500, 256, 0, stream>>>(t2, sums2, g2 + po, bb2 + po, sums3);

        final_k<<<12500, 256, 0, stream>>>(t2, sums2, g2 + po, bb2 + po,
                                           sums3, g3 + po, bb3 + po,
                                           (float4*)out, h16, i * 64);
    }
}

// Round 14
// 949.791 us; speedup vs baseline: 1.1182x; 1.0131x over previous
//
#include <hip/hip_runtime.h>
#include <stdint.h>

#define NN 50000
#define NPAD 50048          // 391*128
#define NE 800000
#define DD 256
#define NL 4

typedef __attribute__((ext_vector_type(8))) _Float16 half8;
typedef __attribute__((ext_vector_type(4))) float f32x4;
typedef __attribute__((ext_vector_type(8))) float f32x8;
typedef __attribute__((ext_vector_type(8))) unsigned short ushort8_t;

__device__ inline unsigned short f2h(float x) {
    union { _Float16 h; unsigned short u; } v;
    v.h = (_Float16)x;
    return v.u;
}
__device__ inline float h2f(unsigned short u) {
    union { unsigned short u; _Float16 h; } v;
    v.u = u;
    return (float)v.h;
}

// async global->LDS, 16B per lane; lds base must be wave-uniform (HW: base + lane*16)
__device__ inline void gload16(const void* g, void* lds_base) {
    __builtin_amdgcn_global_load_lds(
        (const __attribute__((address_space(1))) void*)g,
        (__attribute__((address_space(3))) void*)lds_base,
        16, 0, 0);
}

// swizzled fragment read from linear [R][32]-fp16 LDS tile (64B rows, 4x16B chunks)
__device__ inline const half8* lds_frag(const unsigned short* base_lin, int row, int l4) {
    int chunk = l4 ^ ((row >> 1) & 3);
    return (const half8*)((const char*)base_lin + row * 64 + chunk * 16);
}

// ---- merged one-time setup: h16conv + wconv(W1,W2) + zero sums + zero deg ----
__global__ void setup_k(const float* __restrict__ W1, const float* __restrict__ W2,
                        unsigned short* __restrict__ Wt1, unsigned short* __restrict__ Wt2,
                        const float4* __restrict__ H, unsigned short* __restrict__ h16,
                        float* __restrict__ sums, int* __restrict__ deg) {
    int i = blockIdx.x * 256 + threadIdx.x;   // 0 .. 3.2M-1
    if (i < NN * 64) {
        float4 v = H[i];
        ushort4 u;
        u.x = f2h(v.x); u.y = f2h(v.y); u.z = f2h(v.z); u.w = f2h(v.w);
        *(ushort4*)(h16 + (size_t)i * 4) = u;
    }
    if (i < NL * DD * DD) {
        int l = i >> 16, rem = i & 0xFFFF, k = rem >> 8, n = rem & 255;
        int dst = (l << 16) + (n << 8) + k;
        Wt1[dst] = f2h(W1[i]);
        Wt2[dst] = f2h(W2[i]);
    }
    if (i < NL * 3 * 512) sums[i] = 0.f;
    if (i < NN) deg[i] = 0;
}

// ======================= CSR build (once) =======================
__global__ void hist_k(const int* __restrict__ ei, int* __restrict__ deg) {
    int e = blockIdx.x * 256 + threadIdx.x;
    if (e < NE) atomicAdd(&deg[ei[NE + e]], 1);
}

__global__ void bsum_k(const int* __restrict__ deg, int* __restrict__ bsum) {
    __shared__ int sm[256];
    int i = blockIdx.x * 256 + threadIdx.x;
    sm[threadIdx.x] = (i < NN) ? deg[i] : 0;
    __syncthreads();
    for (int off = 128; off > 0; off >>= 1) {
        if (threadIdx.x < off) sm[threadIdx.x] += sm[threadIdx.x + off];
        __syncthreads();
    }
    if (threadIdx.x == 0) bsum[blockIdx.x] = sm[0];
}

__global__ void bscan_k(const int* __restrict__ bsum, int* __restrict__ boff) {
    __shared__ int sm[256];
    int t = threadIdx.x;
    int v = (t < 196) ? bsum[t] : 0;
    sm[t] = v; __syncthreads();
    for (int off = 1; off < 256; off <<= 1) {
        int u = (t >= off) ? sm[t - off] : 0;
        __syncthreads();
        sm[t] += u;
        __syncthreads();
    }
    boff[t] = sm[t] - v;
}

__global__ void rowptr_k(const int* __restrict__ deg, const int* __restrict__ boff,
                         int* __restrict__ rowptr, int* __restrict__ cursor) {
    __shared__ int sm[256];
    int b = blockIdx.x, t = threadIdx.x;
    int i = b * 256 + t;
    int v = (i < NN) ? deg[i] : 0;
    sm[t] = v; __syncthreads();
    for (int off = 1; off < 256; off <<= 1) {
        int u = (t >= off) ? sm[t - off] : 0;
        __syncthreads();
        sm[t] += u;
        __syncthreads();
    }
    int excl = boff[b] + sm[t] - v;
    if (i < NN) { rowptr[i] = excl; cursor[i] = excl; }
    if (i == NN - 1) rowptr[NN] = excl + v;
}

__global__ void fill_k(const int* __restrict__ ei, int* __restrict__ cursor,
                       int* __restrict__ csr) {
    int e = blockIdx.x * 256 + threadIdx.x;
    if (e < NE) {
        int d = ei[NE + e];
        int p = atomicAdd(&cursor[d], 1);
        csr[p] = ei[e];
    }
}

// ======================= per-layer gather (fp16, 2 rows/wave-step) =======================
__global__ void gather_k(const int* __restrict__ rowptr, const int* __restrict__ csr,
                         const unsigned short* __restrict__ h16,
                         unsigned short* __restrict__ rb) {
    int w    = threadIdx.x >> 6;
    int lane = threadIdx.x & 63;
    int node = blockIdx.x * 4 + w;
    if (node >= NPAD) return;
    int half = lane >> 5;
    int l32  = lane & 31;
    int c    = l32 * 8;
    unsigned short* dst = rb + (size_t)node * DD + c;
    if (node >= NN) {
        if (half == 0) {
            ushort8_t z = {0,0,0,0,0,0,0,0};
            *(ushort8_t*)dst = z;
        }
        return;
    }
    int beg = rowptr[node], end = rowptr[node + 1];
    f32x8 acc = {0.f,0.f,0.f,0.f,0.f,0.f,0.f,0.f};
    if (half == 0) {
        ushort8_t hv = *(const ushort8_t*)(h16 + (size_t)node * DD + c);
        #pragma unroll
        for (int k = 0; k < 8; ++k) acc[k] = h2f(hv[k]);
    }
    int j = beg;
    for (; j + 8 <= end; j += 8) {
        int j0 = csr[j + half], j1 = csr[j + 2 + half];
        int j2 = csr[j + 4 + half], j3 = csr[j + 6 + half];
        ushort8_t v0 = *(const ushort8_t*)(h16 + (size_t)j0 * DD + c);
        ushort8_t v1 = *(const ushort8_t*)(h16 + (size_t)j1 * DD + c);
        ushort8_t v2 = *(const ushort8_t*)(h16 + (size_t)j2 * DD + c);
        ushort8_t v3 = *(const ushort8_t*)(h16 + (size_t)j3 * DD + c);
        #pragma unroll
        for (int k = 0; k < 8; ++k)
            acc[k] += (h2f(v0[k]) + h2f(v1[k])) + (h2f(v2[k]) + h2f(v3[k]));
    }
    for (; j + 2 <= end; j += 2) {
        int jj = csr[j + half];
        ushort8_t v0 = *(const ushort8_t*)(h16 + (size_t)jj * DD + c);
        #pragma unroll
        for (int k = 0; k < 8; ++k) acc[k] += h2f(v0[k]);
    }
    if (j < end && half == 0) {
        int jj = csr[j];
        ushort8_t v0 = *(const ushort8_t*)(h16 + (size_t)jj * DD + c);
        #pragma unroll
        for (int k = 0; k < 8; ++k) acc[k] += h2f(v0[k]);
    }
    #pragma unroll
    for (int k = 0; k < 8; ++k) acc[k] += __shfl_xor(acc[k], 32);
    if (half == 0) {
        ushort8_t u;
        #pragma unroll
        for (int k = 0; k < 8; ++k) u[k] = f2h(acc[k]);
        *(ushort8_t*)dst = u;
    }
}

// =================== GEMM 128x256 tile, 8 waves (2x4), BK=32, fp16 MFMA ===================
#define GEMM_EPILOGUE(CPTR, SUMS)                                                \
    _Pragma("unroll")                                                            \
    for (int nf = 0; nf < 4; ++nf) {                                             \
        int col = wc * 64 + nf * 16 + l15;                                       \
        float bs = bias[col];                                                    \
        float s = 0.f, s2 = 0.f;                                                 \
        _Pragma("unroll")                                                        \
        for (int mf = 0; mf < 4; ++mf) {                                         \
            int r0 = mbase + wr * 64 + mf * 16 + l4 * 4;                         \
            _Pragma("unroll")                                                    \
            for (int j = 0; j < 4; ++j) {                                        \
                int row = r0 + j;                                                \
                if (row < NN) {                                                  \
                    float cv = acc[mf][nf][j] + bs;                              \
                    CPTR[(size_t)row * DD + col] = f2h(cv);                      \
                    s += cv; s2 += cv * cv;                                      \
                }                                                                \
            }                                                                    \
        }                                                                        \
        s  += __shfl_xor(s, 16);  s  += __shfl_xor(s, 32);                       \
        s2 += __shfl_xor(s2, 16); s2 += __shfl_xor(s2, 32);                      \
        if (l4 == 0) {                                                           \
            atomicAdd(&SUMS[col], s);                                            \
            atomicAdd(&SUMS[DD + col], s2);                                      \
        }                                                                        \
    }

// GEMM1: A fp16 (rb, zero-padded rows), t1 = A @ Wt^T + b ; stats -> sums1
__global__ void gemm_f16_k(const unsigned short* __restrict__ A,
                           const unsigned short* __restrict__ Wt,
                           const float* __restrict__ bias,
                           unsigned short* __restrict__ C, float* __restrict__ sums1) {
    __shared__ unsigned short AsL[128 * 32];   // linear, 64B rows
    __shared__ unsigned short BsL[256 * 32];
    const int tid   = threadIdx.x;
    const int mbase = blockIdx.x * 128;
    const int wave  = tid >> 6, lane = tid & 63;
    const int wr = wave >> 2, wc = wave & 3;
    const int l15 = lane & 15, l4 = lane >> 4;

    f32x4 acc[4][4] = {};

    for (int ks = 0; ks < 8; ++ks) {
        const int k0 = ks * 32;
        {
            int q = tid;
            int row = q >> 2, pc = q & 3;
            int gc = pc ^ ((row >> 1) & 3);
            gload16(A + (size_t)(mbase + row) * DD + k0 + gc * 8,
                    AsL + (size_t)wave * 64 * 8);
        }
        #pragma unroll
        for (int p = 0; p < 2; ++p) {
            int q = p * 512 + tid;
            int row = q >> 2, pc = q & 3;
            int gc = pc ^ ((row >> 1) & 3);
            gload16(Wt + (size_t)row * DD + k0 + gc * 8,
                    BsL + ((size_t)p * 512 + (size_t)wave * 64) * 8);
        }
        __syncthreads();
        half8 af[4], bf[4];
        #pragma unroll
        for (int mf = 0; mf < 4; ++mf)
            af[mf] = *lds_frag(AsL, wr * 64 + mf * 16 + l15, l4);
        #pragma unroll
        for (int nf = 0; nf < 4; ++nf)
            bf[nf] = *lds_frag(BsL, wc * 64 + nf * 16 + l15, l4);
        #pragma unroll
        for (int mf = 0; mf < 4; ++mf)
            #pragma unroll
            for (int nf = 0; nf < 4; ++nf)
                acc[mf][nf] = __builtin_amdgcn_mfma_f32_16x16x32_f16(
                    af[mf], bf[nf], acc[mf][nf], 0, 0, 0);
        __syncthreads();
    }
    GEMM_EPILOGUE(C, sums1)
}

// GEMM2: A fp16 (t1); BN1 (inline fin from sums1) + ReLU at staging (padded LDS);
// B staged via global_load_lds (linear+swizzle); stats -> sums2
__global__ void gemm_bn_k(const unsigned short* __restrict__ A,
                          const unsigned short* __restrict__ Wt,
                          const float* __restrict__ bias,
                          const float* __restrict__ sums1,
                          const float* __restrict__ g1, const float* __restrict__ bb1,
                          unsigned short* __restrict__ C, float* __restrict__ sums2) {
    __shared__ unsigned short As[128][40];
    __shared__ unsigned short BsL[256 * 32];
    __shared__ float sc_l[DD], sh_l[DD];
    const int tid   = threadIdx.x;
    const int mbase = blockIdx.x * 128;
    const int wave  = tid >> 6, lane = tid & 63;
    const int wr = wave >> 2, wc = wave & 3;
    const int l15 = lane & 15, l4 = lane >> 4;

    // inline fin1
    if (tid < DD) {
        float s = sums1[tid], s2 = sums1[DD + tid];
        float mu  = s * (1.f / NN);
        float var = s2 * (1.f / NN) - mu * mu;
        float a = rsqrtf(var + 1e-5f) * g1[tid];
        sc_l[tid] = a;
        sh_l[tid] = bb1[tid] - mu * a;
    }

    f32x4 acc[4][4] = {};

    for (int ks = 0; ks < 8; ++ks) {
        const int k0 = ks * 32;
        if (ks == 0) __syncthreads();   // sc_l/sh_l ready
        #pragma unroll
        for (int p = 0; p < 2; ++p) {
            int q = p * 512 + tid;
            int row = q >> 2, pc = q & 3;
            int gc = pc ^ ((row >> 1) & 3);
            gload16(Wt + (size_t)row * DD + k0 + gc * 8,
                    BsL + ((size_t)p * 512 + (size_t)wave * 64) * 8);
        }
        {
            int row = tid >> 2, seg = (tid & 3) * 8;
            int grow = mbase + row;
            uint4 wv = {0u, 0u, 0u, 0u};
            if (grow < NN) wv = *(const uint4*)(A + (size_t)grow * DD + k0 + seg);
            unsigned short* ph = (unsigned short*)&wv;
            int cb = k0 + seg;
            ushort4 u0, u1;
            u0.x = f2h(fmaxf(h2f(ph[0]) * sc_l[cb+0] + sh_l[cb+0], 0.f));
            u0.y = f2h(fmaxf(h2f(ph[1]) * sc_l[cb+1] + sh_l[cb+1], 0.f));
            u0.z = f2h(fmaxf(h2f(ph[2]) * sc_l[cb+2] + sh_l[cb+2], 0.f));
            u0.w = f2h(fmaxf(h2f(ph[3]) * sc_l[cb+3] + sh_l[cb+3], 0.f));
            u1.x = f2h(fmaxf(h2f(ph[4]) * sc_l[cb+4] + sh_l[cb+4], 0.f));
            u1.y = f2h(fmaxf(h2f(ph[5]) * sc_l[cb+5] + sh_l[cb+5], 0.f));
            u1.z = f2h(fmaxf(h2f(ph[6]) * sc_l[cb+6] + sh_l[cb+6], 0.f));
            u1.w = f2h(fmaxf(h2f(ph[7]) * sc_l[cb+7] + sh_l[cb+7], 0.f));
            *(ushort4*)&As[row][seg] = u0;
            *(ushort4*)&As[row][seg + 4] = u1;
        }
        __syncthreads();
        half8 af[4], bf[4];
        #pragma unroll
        for (int mf = 0; mf < 4; ++mf)
            af[mf] = *(const half8*)&As[wr * 64 + mf * 16 + l15][l4 * 8];
        #pragma unroll
        for (int nf = 0; nf < 4; ++nf)
            bf[nf] = *lds_frag(BsL, wc * 64 + nf * 16 + l15, l4);
        #pragma unroll
        for (int mf = 0; mf < 4; ++mf)
            #pragma unroll
            for (int nf = 0; nf < 4; ++nf)
                acc[mf][nf] = __builtin_amdgcn_mfma_f32_16x16x32_f16(
                    af[mf], bf[nf], acc[mf][nf], 0, 0, 0);
        __syncthreads();
    }
    GEMM_EPILOGUE(C, sums2)
}

// ---- BN3 stats over m = relu(BN2(t2)); BN2 inline fin from sums2; stats -> sums3 ----
__global__ void bn_stats_k(const unsigned short* __restrict__ X,
                           const float* __restrict__ sums2,
                           const float* __restrict__ g2, const float* __restrict__ bb2,
                           float* __restrict__ sums3) {
    __shared__ float4 sA[256];
    __shared__ float4 sB[256];
    __shared__ float sc_l[DD], sh_l[DD];
    int t  = threadIdx.x;
    if (t < DD) {
        float s = sums2[t], s2v = sums2[DD + t];
        float mu  = s * (1.f / NN);
        float var = s2v * (1.f / NN) - mu * mu;
        float a = rsqrtf(var + 1e-5f) * g2[t];
        sc_l[t] = a;
        sh_l[t] = bb2[t] - mu * a;
    }
    __syncthreads();
    int rs = t >> 6;
    int c4 = t & 63;
    int c  = c4 * 4;
    float4 a = *(const float4*)(sc_l + c), b = *(const float4*)(sh_l + c);
    float4 s = {0.f,0.f,0.f,0.f}, s2 = {0.f,0.f,0.f,0.f};
    for (int r4 = blockIdx.x; r4 < NN / 4; r4 += gridDim.x) {
        int row = r4 * 4 + rs;
        ushort4 xu = *(const ushort4*)(X + (size_t)row * DD + c);
        float4 m;
        m.x = fmaxf(h2f(xu.x) * a.x + b.x, 0.f);
        m.y = fmaxf(h2f(xu.y) * a.y + b.y, 0.f);
        m.z = fmaxf(h2f(xu.z) * a.z + b.z, 0.f);
        m.w = fmaxf(h2f(xu.w) * a.w + b.w, 0.f);
        s.x += m.x; s.y += m.y; s.z += m.z; s.w += m.w;
        s2.x += m.x*m.x; s2.y += m.y*m.y; s2.z += m.z*m.z; s2.w += m.w*m.w;
    }
    sA[t] = s; sB[t] = s2;
    __syncthreads();
    if (t < 128) {
        sA[t].x += sA[t+128].x; sA[t].y += sA[t+128].y; sA[t].z += sA[t+128].z; sA[t].w += sA[t+128].w;
        sB[t].x += sB[t+128].x; sB[t].y += sB[t+128].y; sB[t].z += sB[t+128].z; sB[t].w += sB[t+128].w;
    }
    __syncthreads();
    if (t < 64) {
        float4 fs, fs2;
        fs.x = sA[t].x + sA[t+64].x; fs.y = sA[t].y + sA[t+64].y;
        fs.z = sA[t].z + sA[t+64].z; fs.w = sA[t].w + sA[t+64].w;
        fs2.x = sB[t].x + sB[t+64].x; fs2.y = sB[t].y + sB[t+64].y;
        fs2.z = sB[t].z + sB[t+64].z; fs2.w = sB[t].w + sB[t+64].w;
        atomicAdd(&sums3[c + 0], fs.x);  atomicAdd(&sums3[c + 1], fs.y);
        atomicAdd(&sums3[c + 2], fs.z);  atomicAdd(&sums3[c + 3], fs.w);
        atomicAdd(&sums3[DD + c + 0], fs2.x); atomicAdd(&sums3[DD + c + 1], fs2.y);
        atomicAdd(&sums3[DD + c + 2], fs2.z); atomicAdd(&sums3[DD + c + 3], fs2.w);
    }
}

// ---- final: h = relu(BN3(relu(BN2(t2)))); BN2/BN3 inline fin; write out (+h16 unless last) ----
__global__ void final_k(const unsigned short* __restrict__ T2,
                        const float* __restrict__ sums2,
                        const float* __restrict__ g2, const float* __restrict__ bb2,
                        const float* __restrict__ sums3,
                        const float* __restrict__ g3, const float* __restrict__ bb3,
                        float4* __restrict__ Out, unsigned short* __restrict__ h16,
                        int loff4, int write_h16) {
    __shared__ float sc2_l[DD], sh2_l[DD], sc3_l[DD], sh3_l[DD];
    int t = threadIdx.x;
    if (t < DD) {
        float s = sums2[t], s2v = sums2[DD + t];
        float mu  = s * (1.f / NN);
        float var = s2v * (1.f / NN) - mu * mu;
        float a = rsqrtf(var + 1e-5f) * g2[t];
        sc2_l[t] = a;
        sh2_l[t] = bb2[t] - mu * a;
        s = sums3[t]; s2v = sums3[DD + t];
        mu  = s * (1.f / NN);
        var = s2v * (1.f / NN) - mu * mu;
        a = rsqrtf(var + 1e-5f) * g3[t];
        sc3_l[t] = a;
        sh3_l[t] = bb3[t] - mu * a;
    }
    __syncthreads();
    int i = blockIdx.x * 256 + t;             // over NN*64
    int row = i >> 6, c4 = i & 63;
    int c = c4 * 4;
    ushort4 xu = *(const ushort4*)(T2 + (size_t)i * 4);
    float4 a2 = *(const float4*)(sc2_l + c), b2 = *(const float4*)(sh2_l + c);
    float4 a3 = *(const float4*)(sc3_l + c), b3 = *(const float4*)(sh3_l + c);
    float4 m, h;
    m.x = fmaxf(h2f(xu.x) * a2.x + b2.x, 0.f);
    m.y = fmaxf(h2f(xu.y) * a2.y + b2.y, 0.f);
    m.z = fmaxf(h2f(xu.z) * a2.z + b2.z, 0.f);
    m.w = fmaxf(h2f(xu.w) * a2.w + b2.w, 0.f);
    h.x = fmaxf(m.x * a3.x + b3.x, 0.f);
    h.y = fmaxf(m.y * a3.y + b3.y, 0.f);
    h.z = fmaxf(m.z * a3.z + b3.z, 0.f);
    h.w = fmaxf(m.w * a3.w + b3.w, 0.f);
    Out[(size_t)row * 256 + loff4 + c4] = h;
    if (write_h16) {
        ushort4 u;
        u.x = f2h(h.x); u.y = f2h(h.y); u.z = f2h(h.z); u.w = f2h(h.w);
        *(ushort4*)(h16 + (size_t)i * 4) = u;
    }
}

extern "C" void kernel_launch(void* const* d_in, const int* in_sizes, int n_in,
                              void* d_out, int out_size, void* d_ws, size_t ws_size,
                              hipStream_t stream) {
    const float* h_in = (const float*)d_in[0];
    const int*   ei   = (const int*)d_in[1];
    const float* W1   = (const float*)d_in[2];
    const float* b1   = (const float*)d_in[3];
    const float* W2   = (const float*)d_in[4];
    const float* b2   = (const float*)d_in[5];
    const float* g1   = (const float*)d_in[6];
    const float* bb1  = (const float*)d_in[7];
    const float* g2   = (const float*)d_in[8];
    const float* bb2  = (const float*)d_in[9];
    const float* g3   = (const float*)d_in[10];
    const float* bb3  = (const float*)d_in[11];
    float* out = (float*)d_out;

    const size_t SZ = (size_t)NN * DD;
    unsigned short* t1  = (unsigned short*)d_ws;               // NN*DD fp16
    unsigned short* t2  = t1 + SZ;                             // NN*DD fp16
    unsigned short* rb  = t2 + SZ;                             // NPAD*DD fp16
    unsigned short* h16 = rb + (size_t)NPAD * DD;              // NN*DD fp16
    unsigned short* Wt1 = h16 + SZ;
    unsigned short* Wt2 = Wt1 + (size_t)NL * DD * DD;
    float* sums_all = (float*)(Wt2 + (size_t)NL * DD * DD);    // 12*512 floats
    int* deg    = (int*)(sums_all + NL * 3 * 512);
    int* bsum   = deg + NN;          // 196 (pad 256)
    int* boff   = bsum + 256;        // 256
    int* rowptr = boff + 256;        // NN+1
    int* cursor = rowptr + NN + 1;   // NN
    int* csr    = cursor + NN;       // NE

    // one-time setup (merged) + CSR build
    setup_k<<<12500, 256, 0, stream>>>(W1, W2, Wt1, Wt2, (const float4*)h_in, h16,
                                       sums_all, deg);
    hist_k<<<(NE + 255) / 256, 256, 0, stream>>>(ei, deg);
    bsum_k<<<196, 256, 0, stream>>>(deg, bsum);
    bscan_k<<<1, 256, 0, stream>>>(bsum, boff);
    rowptr_k<<<196, 256, 0, stream>>>(deg, boff, rowptr, cursor);
    fill_k<<<(NE + 255) / 256, 256, 0, stream>>>(ei, cursor, csr);

    for (int i = 0; i < NL; ++i) {
        float* sums1 = sums_all + (size_t)i * 1536;
        float* sums2 = sums1 + 512;
        float* sums3 = sums2 + 512;
        const size_t po = (size_t)i * DD;

        gather_k<<<NPAD / 4, 256, 0, stream>>>(rowptr, csr, h16, rb);

        gemm_f16_k<<<NPAD / 128, 512, 0, stream>>>(
            rb, Wt1 + (size_t)i * DD * DD, b1 + po, t1, sums1);

        gemm_bn_k<<<NPAD / 128, 512, 0, stream>>>(
            t1, Wt2 + (size_t)i * DD * DD, b2 + po, sums1, g1 + po, bb1 + po, t2, sums2);

        bn_stats_k<<<500, 256, 0, stream>>>(t2, sums2, g2 + po, bb2 + po, sums3);

        final_k<<<12500, 256, 0, stream>>>(t2, sums2, g2 + po, bb2 + po,
                                           sums3, g3 + po, bb3 + po,
                                           (float4*)out, h16, i * 64,
                                           (i < NL - 1) ? 1 : 0);
    }
}